// Round 9
// baseline (1745.626 us; speedup 1.0000x reference)
//
#include <hip/hip_runtime.h>
#include <hip/hip_bf16.h>

#define B_  16
#define N_  512
#define K_  512
#define HF_ 512
#define NH_ 8

// ---- numpy f32 emulation helpers (explicit roundings; no contraction) ----
__device__ __forceinline__ float f_add(float a, float b){ return __fadd_rn(a,b); }
__device__ __forceinline__ float f_sub(float a, float b){ return __fsub_rn(a,b); }
__device__ __forceinline__ float f_mul(float a, float b){ return __fmul_rn(a,b); }
__device__ __forceinline__ float f_fma(float a, float b, float c){ return __fmaf_rn(a,b,c); }
__device__ __forceinline__ float f_div(float a, float b){ return __fdiv_rn(a,b); }
// correctly-rounded f32 exp via f64
__device__ __forceinline__ float expf_cr(float x){ return (float)exp((double)x); }
// leaky: np.where(x>=0, x, 0.1*x) with f32 scalar 0.1
__device__ __forceinline__ float lrelu_np(float x){ return x >= 0.f ? x : f_mul(0.1f, x); }

// numpy pairwise_sum for a 128-block: 8 accumulators + fixed combine tree
__device__ float pw128(const float* x){
  float r0=x[0],r1=x[1],r2=x[2],r3=x[3],r4=x[4],r5=x[5],r6=x[6],r7=x[7];
  for (int i=8;i<128;i+=8){
    r0=f_add(r0,x[i+0]); r1=f_add(r1,x[i+1]); r2=f_add(r2,x[i+2]); r3=f_add(r3,x[i+3]);
    r4=f_add(r4,x[i+4]); r5=f_add(r5,x[i+5]); r6=f_add(r6,x[i+6]); r7=f_add(r7,x[i+7]);
  }
  return f_add(f_add(f_add(r0,r1),f_add(r2,r3)), f_add(f_add(r4,r5),f_add(r6,r7)));
}
// numpy pairwise_sum(512) = (pw128+pw128) + (pw128+pw128)
__device__ float pw512(const float* x){
  return f_add(f_add(pw128(x),pw128(x+128)), f_add(pw128(x+256),pw128(x+384)));
}

// ---- sgemm emu: C[m,c] = sequential-k fused-FMA chain (OpenBLAS microkernel order) ----
__global__ __launch_bounds__(256) void gemm_emu(const float* __restrict__ A, const float* __restrict__ W,
                                                float* __restrict__ C, int M){
  const int g = blockIdx.x*256 + threadIdx.x;
  if (g >= M*HF_) return;
  const int m = g >> 9, c = g & 511;
  const float* ar = A + (size_t)m*K_;
  float acc = 0.f;
  for (int k=0;k<K_;++k) acc = f_fma(ar[k], W[(size_t)k*HF_ + c], acc);
  C[(size_t)m*HF_ + c] = acc;
}

// ---- el/er: einsum 'bnhf,f->bnh' — sequential f ascending, mul+add separate roundings ----
__global__ __launch_bounds__(256) void eler_emu(const float* __restrict__ g, const float* __restrict__ a,
                                                float* __restrict__ el, float* __restrict__ er){
  const int gid = blockIdx.x*256 + threadIdx.x;   // (row, h)
  const int row = gid >> 3, h = gid & 7;
  const float* gr = g + (size_t)row*HF_ + h*64;
  float pl = 0.f, pr = 0.f;
  for (int f=0; f<64; ++f){
    pl = f_add(pl, f_mul(gr[f], a[f]));
    pr = f_add(pr, f_mul(gr[f], a[64+f]));
  }
  el[(size_t)row*NH_+h] = pl;
  er[(size_t)row*NH_+h] = pr;
}

// ---- attention row: block(64) per (bc,h,i). Emulates masked-softmax + einsum aggregation ----
// e = leaky(el_i + er_j); mask -> -1000; m = max_j; p = exp(e-m); den = np-pairwise-512;
// att = p/den; out[f] = leaky( sum_j seq( att_j * g[j,f] ) )  [mul+add separate roundings]
__global__ __launch_bounds__(64) void att_emu(const float* __restrict__ g, const float* __restrict__ el,
                                              const float* __restrict__ er, const float* __restrict__ adjc,
                                              float* __restrict__ hout){
  const int bid = blockIdx.x;
  const int i  = bid & 511, h = (bid>>9)&7, bc = bid>>12;
  __shared__ float w[512];
  __shared__ float red[64];
  __shared__ float den_s;
  const int t = threadIdx.x;
  const float eli = el[(size_t)(bc*N_+i)*NH_+h];
  // phase 1: masked e
  for (int jj=0;jj<8;++jj){
    const int j = jj*64 + t;
    const float erj = er[(size_t)(bc*N_+j)*NH_+h];
    const float av  = adjc[(size_t)(bc*N_+i)*N_ + j];
    const bool mask = (av != 0.f) || (i == j);
    float e = lrelu_np(f_add(eli, erj));
    w[j] = mask ? e : -1000.0f;
  }
  __syncthreads();
  // phase 2: m = max_j (exact, order-free)
  float mx = w[t];
  for (int jj=1;jj<8;++jj) mx = fmaxf(mx, w[jj*64+t]);
  red[t] = mx;
  __syncthreads();
  for (int s=32;s>=1;s>>=1){ if (t<s) red[t] = fmaxf(red[t], red[t+s]); __syncthreads(); }
  const float m = red[0];
  __syncthreads();
  // phase 3: p = exp(e - m)
  for (int jj=0;jj<8;++jj){
    const int j = jj*64 + t;
    w[j] = expf_cr(f_sub(w[j], m));
  }
  __syncthreads();
  // phase 4: den = numpy pairwise over j ascending
  if (t==0) den_s = pw512(w);
  __syncthreads();
  const float den = den_s;
  __syncthreads();
  // phase 5: att = p/den (IEEE f32 div)
  for (int jj=0;jj<8;++jj){
    const int j = jj*64 + t;
    w[j] = f_div(w[j], den);
  }
  __syncthreads();
  // phase 6: out[f] = leaky( seq-sum_j att_j*g[j, h*64+f] ), f = t
  float acc = 0.f;
  const float* gcol = g + (size_t)bc*N_*HF_ + h*64 + t;
  for (int j=0;j<512;++j) acc = f_add(acc, f_mul(w[j], gcol[(size_t)j*HF_]));
  hout[(size_t)(bc*N_+i)*HF_ + h*64 + t] = lrelu_np(acc);
}

// ---- scores: sgemv_t 8-lane emulation: q[l] over k≡l (mod 8), fixed horizontal tree; +bp ----
__global__ __launch_bounds__(256) void scores_emu(const float* __restrict__ h2, const float* __restrict__ Wp,
                                                  const float* __restrict__ bp, float* __restrict__ sc){
  const int r = blockIdx.x*256 + threadIdx.x;   // (bc, n)
  const float* hr = h2 + (size_t)r*HF_;
  float q0=0,q1=0,q2=0,q3=0,q4=0,q5=0,q6=0,q7=0;
  for (int k=0;k<512;k+=8){
    q0=f_fma(hr[k+0],Wp[k+0],q0); q1=f_fma(hr[k+1],Wp[k+1],q1);
    q2=f_fma(hr[k+2],Wp[k+2],q2); q3=f_fma(hr[k+3],Wp[k+3],q3);
    q4=f_fma(hr[k+4],Wp[k+4],q4); q5=f_fma(hr[k+5],Wp[k+5],q5);
    q6=f_fma(hr[k+6],Wp[k+6],q6); q7=f_fma(hr[k+7],Wp[k+7],q7);
  }
  // vextract+add (l,l+4), haddps, haddps
  const float d = f_add(f_add(f_add(q0,q4),f_add(q1,q5)), f_add(f_add(q2,q6),f_add(q3,q7)));
  sc[r] = f_add(d, bp[0]);
}

// ---- stable top-256 rank counting on f32 scores (ties -> lower index) ----
__global__ __launch_bounds__(512) void topk_f(const float* __restrict__ sc, int* __restrict__ idx){
  __shared__ float sl[512];
  const int b = blockIdx.x, t = threadIdx.x;
  if (t < 256) idx[b*256+t] = t;
  sl[t] = sc[(size_t)b*N_+t];
  __syncthreads();
  const float mine = sl[t];
  int cnt = 0;
  for (int j=0;j<N_;++j){
    const float v = sl[j];
    cnt += (v > mine) || (v == mine && j < t);
  }
  if (cnt < 256) idx[b*256+cnt] = t;
}

__global__ __launch_bounds__(128) void gather_f(const float* __restrict__ h2, const int* __restrict__ idx,
                                                float* __restrict__ outc){
  const int r = blockIdx.x;
  const int bc = r>>8, kk = r&255;
  const int n = idx[bc*256+kk] & (N_-1);
  const int t = threadIdx.x;
  const float4 v = *reinterpret_cast<const float4*>(&h2[(size_t)(bc*N_+n)*HF_ + t*4]);
  *reinterpret_cast<float4*>(&outc[(size_t)(bc*256+kk)*HF_ + t*4]) = v;
}

extern "C" void kernel_launch(void* const* d_in, const int* in_sizes, int n_in,
                              void* d_out, int out_size, void* d_ws, size_t ws_size,
                              hipStream_t stream){
  const float* x   = (const float*)d_in[0];
  const float* adj = (const float*)d_in[1];
  const float* W1  = (const float*)d_in[2];
  const float* a1  = (const float*)d_in[3];
  const float* W2  = (const float*)d_in[4];
  const float* a2  = (const float*)d_in[5];
  const float* Wp  = (const float*)d_in[6];
  const float* bp  = (const float*)d_in[7];

  // per-batch: g 1MiB + h1 1MiB + h2 1MiB + el 16KiB + er 16KiB + sc 2KiB + idx 1KiB
  const size_t per = 3*1048576 + 2*16384 + 2048 + 1024;
  int C = B_;
  while (C > 1 && per*(size_t)C > ws_size) C >>= 1;

  char* w    = (char*)d_ws;
  float* g   = (float*)w;
  float* h1  = (float*)(w + (size_t)C*1048576);
  float* h2  = (float*)(w + (size_t)2*C*1048576);
  float* el  = (float*)(w + (size_t)3*C*1048576);
  float* er  = el + (size_t)C*4096;
  float* sc  = er + (size_t)C*4096;
  int*  idx  = (int*)(sc + (size_t)C*512);

  for (int b0 = 0; b0 < B_; b0 += C){
    const float* xc   = x   + (size_t)b0*N_*K_;
    const float* adjc = adj + (size_t)b0*N_*N_;
    float* outc = (float*)d_out + (size_t)b0*256*HF_;
    const int M = C*N_;
    // layer 1
    gemm_emu<<<(M*HF_)/256, 256, 0, stream>>>(xc, W1, g, M);
    eler_emu<<<(M*NH_)/256, 256, 0, stream>>>(g, a1, el, er);
    att_emu<<<C*NH_*N_, 64, 0, stream>>>(g, el, er, adjc, h1);
    // layer 2
    gemm_emu<<<(M*HF_)/256, 256, 0, stream>>>(h1, W2, g, M);
    eler_emu<<<(M*NH_)/256, 256, 0, stream>>>(g, a2, el, er);
    att_emu<<<C*NH_*N_, 64, 0, stream>>>(g, el, er, adjc, h2);
    // pool
    scores_emu<<<M/256, 256, 0, stream>>>(h2, Wp, bp, sc);
    topk_f<<<C, 512, 0, stream>>>(sc, idx);
    gather_f<<<C*256, 128, 0, stream>>>(h2, idx, outc);
  }
}

// Round 10
// 582.056 us; speedup vs baseline: 2.9991x; 2.9991x over previous
//
#include <hip/hip_runtime.h>
#include <hip/hip_bf16.h>

#define B_  16
#define N_  512
#define K_  512
#define HF_ 512
#define NH_ 8

// ---- numpy f32 emulation helpers (explicit roundings; no contraction) ----
__device__ __forceinline__ float f_add(float a, float b){ return __fadd_rn(a,b); }
__device__ __forceinline__ float f_sub(float a, float b){ return __fsub_rn(a,b); }
__device__ __forceinline__ float f_mul(float a, float b){ return __fmul_rn(a,b); }
__device__ __forceinline__ float f_fma(float a, float b, float c){ return __fmaf_rn(a,b,c); }
__device__ __forceinline__ float f_div(float a, float b){ return __fdiv_rn(a,b); }
__device__ __forceinline__ float expf_cr(float x){ return (float)exp((double)x); }
__device__ __forceinline__ float lrelu_np(float x){ return x >= 0.f ? x : f_mul(0.1f, x); }

// ---- sgemm emu, tiled. Per-element FP: sequential-k fused-FMA chain (identical to r9). ----
// Tile M32 x C64, BK=16. 256 threads; thread handles 2m x 4c = 8 independent chains.
__global__ __launch_bounds__(256) void gemm_t(const float* __restrict__ A, const float* __restrict__ W,
                                              float* __restrict__ C){
  __shared__ float As[32][17];
  __shared__ float Ws[16][68];   // 68: keeps float4 reads 16B-aligned
  const int t  = threadIdx.x;
  const int c0 = blockIdx.x*64, m0 = blockIdx.y*32;
  const int mb = t>>4;           // 0..15 -> rows mb, mb+16
  const int c4 = (t&15)*4;       // 4 consecutive c
  float acc[2][4] = {};
  for (int kt=0; kt<K_; kt+=16){
    {
      const int row = t>>3, kk = (t&7)*2;
      const float* ap = A + (size_t)(m0+row)*K_ + kt + kk;
      As[row][kk] = ap[0]; As[row][kk+1] = ap[1];
    }
    #pragma unroll
    for (int s2=0;s2<4;++s2){
      const int idx = t + 256*s2;
      const int r = idx>>6, cc = idx&63;
      Ws[r][cc] = W[(size_t)(kt+r)*HF_ + c0 + cc];
    }
    __syncthreads();
    #pragma unroll
    for (int k=0;k<16;++k){
      const float a0 = As[mb][k];
      const float a1 = As[mb+16][k];
      const float4 wv = *reinterpret_cast<const float4*>(&Ws[k][c4]);
      acc[0][0]=f_fma(a0,wv.x,acc[0][0]); acc[0][1]=f_fma(a0,wv.y,acc[0][1]);
      acc[0][2]=f_fma(a0,wv.z,acc[0][2]); acc[0][3]=f_fma(a0,wv.w,acc[0][3]);
      acc[1][0]=f_fma(a1,wv.x,acc[1][0]); acc[1][1]=f_fma(a1,wv.y,acc[1][1]);
      acc[1][2]=f_fma(a1,wv.z,acc[1][2]); acc[1][3]=f_fma(a1,wv.w,acc[1][3]);
    }
    __syncthreads();
  }
  #pragma unroll
  for (int q=0;q<2;++q){
    float4 o = make_float4(acc[q][0],acc[q][1],acc[q][2],acc[q][3]);
    *reinterpret_cast<float4*>(&C[(size_t)(m0+mb+16*q)*HF_ + c0 + c4]) = o;
  }
}

// ---- el/er: unchanged from r9 (sequential f ascending, mul+add separate) ----
__global__ __launch_bounds__(256) void eler_emu(const float* __restrict__ g, const float* __restrict__ a,
                                                float* __restrict__ el, float* __restrict__ er){
  const int gid = blockIdx.x*256 + threadIdx.x;   // (row, h)
  const int row = gid >> 3, h = gid & 7;
  const float* gr = g + (size_t)row*HF_ + h*64;
  float pl = 0.f, pr = 0.f;
  for (int f=0; f<64; ++f){
    pl = f_add(pl, f_mul(gr[f], a[f]));
    pr = f_add(pr, f_mul(gr[f], a[64+f]));
  }
  el[(size_t)row*NH_+h] = pl;
  er[(size_t)row*NH_+h] = pr;
}

// ---- attention, i-tiled: block per (bc, h, 16-row i-tile), 256 threads.
// Per-element FP identical to r9 att_emu: e=lrelu(el+er) masked -1000; m=max_j (order-free);
// p=exp_cr(e-m); den=numpy pw512 (8-acc + fixed tree); att=p/den; out=lrelu(seq-j sum att*g). ----
__global__ __launch_bounds__(256) void att_tile(const float* __restrict__ g, const float* __restrict__ el,
                                                const float* __restrict__ er, const float* __restrict__ adjc,
                                                float* __restrict__ hout){
  const int bid = blockIdx.x;
  const int it = bid & 31, h = (bid>>5)&7, bc = bid>>8;
  const int i0 = it*16;
  __shared__ float er_s[512];
  __shared__ float p_s[16][513];
  __shared__ float el_s[16];
  __shared__ float red[256];
  __shared__ float rs[16][33];
  __shared__ float m_s[16], den_s[16];
  const int t = threadIdx.x;
  if (t < 16) el_s[t] = el[((size_t)(bc*N_) + i0 + t)*NH_ + h];
  er_s[t]     = er[((size_t)(bc*N_) + t)*NH_ + h];
  er_s[t+256] = er[((size_t)(bc*N_) + t + 256)*NH_ + h];
  __syncthreads();
  // e (masked), all 16 rows
  for (int i=0;i<16;++i){
    const float eli = el_s[i];
    const int gi = i0 + i;
    #pragma unroll
    for (int s=0;s<2;++s){
      const int j = t + s*256;
      const float av = adjc[((size_t)(bc*N_)+gi)*N_ + j];
      const bool mask = (av != 0.f) || (gi == j);
      float e = lrelu_np(f_add(eli, er_s[j]));
      p_s[i][j] = mask ? e : -1000.0f;
    }
  }
  __syncthreads();
  // row max (order-free, exact): 16 lanes per row, strided scan, then tree
  {
    const int i = t>>4, l = t&15;
    float mx = p_s[i][l];
    for (int u=1;u<32;++u) mx = fmaxf(mx, p_s[i][l + 16*u]);
    red[t] = mx;
  }
  __syncthreads();
  if (t < 128){ const int i=t>>3, l=t&7; red[i*16+l] = fmaxf(red[i*16+l], red[i*16+l+8]); }
  __syncthreads();
  if (t < 64){ const int i=t>>2, l=t&3; red[i*16+l] = fmaxf(red[i*16+l], red[i*16+l+4]); }
  __syncthreads();
  if (t < 32){ const int i=t>>1, l=t&1; red[i*16+l] = fmaxf(red[i*16+l], red[i*16+l+2]); }
  __syncthreads();
  if (t < 16) m_s[t] = fmaxf(red[t*16], red[t*16+1]);
  __syncthreads();
  // p = exp_cr(e - m)
  for (int i=0;i<16;++i){
    const float mi = m_s[i];
    #pragma unroll
    for (int s=0;s<2;++s){
      const int j = t + s*256;
      p_s[i][j] = expf_cr(f_sub(p_s[i][j], mi));
    }
  }
  __syncthreads();
  // den: numpy pairwise — accumulator slot (g,l): r = sum_{m=0..15} p[g*128+m*8+l], seq ascending
  {
    const int i = t>>4;
    #pragma unroll
    for (int ss=0;ss<2;++ss){
      const int s = (t&15) + ss*16;
      const int gq = s>>3, l = s&7;
      float r = p_s[i][gq*128 + l];
      for (int m2=1;m2<16;++m2) r = f_add(r, p_s[i][gq*128 + m2*8 + l]);
      rs[i][s] = r;
    }
  }
  __syncthreads();
  if (t < 16){
    const int i = t;
    float pw[4];
    #pragma unroll
    for (int gq=0;gq<4;++gq){
      const float* rr = &rs[i][gq*8];
      pw[gq] = f_add(f_add(f_add(rr[0],rr[1]),f_add(rr[2],rr[3])),
                     f_add(f_add(rr[4],rr[5]),f_add(rr[6],rr[7])));
    }
    den_s[i] = f_add(f_add(pw[0],pw[1]), f_add(pw[2],pw[3]));
  }
  __syncthreads();
  // att = p/den
  for (int i=0;i<16;++i){
    const float di = den_s[i];
    #pragma unroll
    for (int s=0;s<2;++s){
      const int j = t + s*256;
      p_s[i][j] = f_div(p_s[i][j], di);
    }
  }
  __syncthreads();
  // aggregation: thread = (f = t&63, iw = t>>6); 4 chains i = iw+4q; 1 g-load shared by 4 chains
  {
    const int f = t & 63, iw = t >> 6;
    float a0=0.f, a1=0.f, a2=0.f, a3=0.f;
    const float* gcol = g + (size_t)(bc*N_)*HF_ + h*64 + f;
    #pragma unroll 8
    for (int j=0;j<512;++j){
      const float gv = gcol[(size_t)j*HF_];
      a0 = f_add(a0, f_mul(p_s[iw   ][j], gv));
      a1 = f_add(a1, f_mul(p_s[iw+4 ][j], gv));
      a2 = f_add(a2, f_mul(p_s[iw+8 ][j], gv));
      a3 = f_add(a3, f_mul(p_s[iw+12][j], gv));
    }
    const size_t ob = (size_t)(bc*N_) + i0;
    hout[(ob+iw   )*HF_ + h*64 + f] = lrelu_np(a0);
    hout[(ob+iw+4 )*HF_ + h*64 + f] = lrelu_np(a1);
    hout[(ob+iw+8 )*HF_ + h*64 + f] = lrelu_np(a2);
    hout[(ob+iw+12)*HF_ + h*64 + f] = lrelu_np(a3);
  }
}

// ---- scores: unchanged from r9 (8-lane sgemv emulation + fixed tree + bp) ----
__global__ __launch_bounds__(256) void scores_emu(const float* __restrict__ h2, const float* __restrict__ Wp,
                                                  const float* __restrict__ bp, float* __restrict__ sc){
  const int r = blockIdx.x*256 + threadIdx.x;   // (bc, n)
  const float* hr = h2 + (size_t)r*HF_;
  float q0=0,q1=0,q2=0,q3=0,q4=0,q5=0,q6=0,q7=0;
  for (int k=0;k<512;k+=8){
    q0=f_fma(hr[k+0],Wp[k+0],q0); q1=f_fma(hr[k+1],Wp[k+1],q1);
    q2=f_fma(hr[k+2],Wp[k+2],q2); q3=f_fma(hr[k+3],Wp[k+3],q3);
    q4=f_fma(hr[k+4],Wp[k+4],q4); q5=f_fma(hr[k+5],Wp[k+5],q5);
    q6=f_fma(hr[k+6],Wp[k+6],q6); q7=f_fma(hr[k+7],Wp[k+7],q7);
  }
  const float d = f_add(f_add(f_add(q0,q4),f_add(q1,q5)), f_add(f_add(q2,q6),f_add(q3,q7)));
  sc[r] = f_add(d, bp[0]);
}

// ---- stable top-256 rank counting (unchanged) ----
__global__ __launch_bounds__(512) void topk_f(const float* __restrict__ sc, int* __restrict__ idx){
  __shared__ float sl[512];
  const int b = blockIdx.x, t = threadIdx.x;
  if (t < 256) idx[b*256+t] = t;
  sl[t] = sc[(size_t)b*N_+t];
  __syncthreads();
  const float mine = sl[t];
  int cnt = 0;
  for (int j=0;j<N_;++j){
    const float v = sl[j];
    cnt += (v > mine) || (v == mine && j < t);
  }
  if (cnt < 256) idx[b*256+cnt] = t;
}

__global__ __launch_bounds__(128) void gather_f(const float* __restrict__ h2, const int* __restrict__ idx,
                                                float* __restrict__ outc){
  const int r = blockIdx.x;
  const int bc = r>>8, kk = r&255;
  const int n = idx[bc*256+kk] & (N_-1);
  const int t = threadIdx.x;
  const float4 v = *reinterpret_cast<const float4*>(&h2[(size_t)(bc*N_+n)*HF_ + t*4]);
  *reinterpret_cast<float4*>(&outc[(size_t)(bc*256+kk)*HF_ + t*4]) = v;
}

extern "C" void kernel_launch(void* const* d_in, const int* in_sizes, int n_in,
                              void* d_out, int out_size, void* d_ws, size_t ws_size,
                              hipStream_t stream){
  const float* x   = (const float*)d_in[0];
  const float* adj = (const float*)d_in[1];
  const float* W1  = (const float*)d_in[2];
  const float* a1  = (const float*)d_in[3];
  const float* W2  = (const float*)d_in[4];
  const float* a2  = (const float*)d_in[5];
  const float* Wp  = (const float*)d_in[6];
  const float* bp  = (const float*)d_in[7];

  const size_t per = 3*1048576 + 2*16384 + 2048 + 1024;
  int C = B_;
  while (C > 1 && per*(size_t)C > ws_size) C >>= 1;

  char* w    = (char*)d_ws;
  float* g   = (float*)w;
  float* h1  = (float*)(w + (size_t)C*1048576);
  float* h2  = (float*)(w + (size_t)2*C*1048576);
  float* el  = (float*)(w + (size_t)3*C*1048576);
  float* er  = el + (size_t)C*4096;
  float* sc  = er + (size_t)C*4096;
  int*  idx  = (int*)(sc + (size_t)C*512);

  for (int b0 = 0; b0 < B_; b0 += C){
    const float* xc   = x   + (size_t)b0*N_*K_;
    const float* adjc = adj + (size_t)b0*N_*N_;
    float* outc = (float*)d_out + (size_t)b0*256*HF_;
    const int M = C*N_;
    dim3 gg(HF_/64, M/32);
    // layer 1
    gemm_t<<<gg, 256, 0, stream>>>(xc, W1, g);
    eler_emu<<<(M*NH_)/256, 256, 0, stream>>>(g, a1, el, er);
    att_tile<<<C*NH_*32, 256, 0, stream>>>(g, el, er, adjc, h1);
    // layer 2
    gemm_t<<<gg, 256, 0, stream>>>(h1, W2, g);
    eler_emu<<<(M*NH_)/256, 256, 0, stream>>>(g, a2, el, er);
    att_tile<<<C*NH_*32, 256, 0, stream>>>(g, el, er, adjc, h2);
    // pool
    scores_emu<<<M/256, 256, 0, stream>>>(h2, Wp, bp, sc);
    topk_f<<<C, 512, 0, stream>>>(sc, idx);
    gather_f<<<C*256, 128, 0, stream>>>(h2, idx, outc);
  }
}

// Round 11
// 566.760 us; speedup vs baseline: 3.0800x; 1.0270x over previous
//
#include <hip/hip_runtime.h>
#include <hip/hip_bf16.h>

#define B_  16
#define N_  512
#define K_  512
#define HF_ 512
#define NH_ 8

// ---- numpy f32 emulation helpers (explicit roundings; no contraction) ----
__device__ __forceinline__ float f_add(float a, float b){ return __fadd_rn(a,b); }
__device__ __forceinline__ float f_sub(float a, float b){ return __fsub_rn(a,b); }
__device__ __forceinline__ float f_mul(float a, float b){ return __fmul_rn(a,b); }
__device__ __forceinline__ float f_fma(float a, float b, float c){ return __fmaf_rn(a,b,c); }
__device__ __forceinline__ float f_div(float a, float b){ return __fdiv_rn(a,b); }
__device__ __forceinline__ float expf_cr(float x){ return (float)exp((double)x); }
__device__ __forceinline__ float lrelu_np(float x){ return x >= 0.f ? x : f_mul(0.1f, x); }

// XCD-aware chunked block swizzle (bijective: all grids here are multiples of 8).
// Default dispatch round-robins consecutive blocks across the 8 XCDs; this remap gives
// each XCD a CONTIGUOUS logical range so same-bc blocks share a per-XCD L2 working set.
__device__ __forceinline__ int swz8(int phys, int nwg){
  const int cpx = nwg >> 3;
  return (phys & 7)*cpx + (phys >> 3);
}

// ---- sgemm emu, tiled. Per-element FP: sequential-k fused-FMA chain (identical). ----
// Tile M32 x C64, BK=16. 256 threads; thread handles 2m x 4c = 8 independent chains.
__global__ __launch_bounds__(256) void gemm_t(const float* __restrict__ A, const float* __restrict__ W,
                                              float* __restrict__ C){
  __shared__ float As[32][17];
  __shared__ float Ws[16][68];   // 68: keeps float4 reads 16B-aligned
  const int t  = threadIdx.x;
  const int nb = gridDim.x*gridDim.y;
  const int id = swz8(blockIdx.y*gridDim.x + blockIdx.x, nb);
  const int c0 = (id & 7)*64, m0 = (id >> 3)*32;
  const int mb = t>>4;           // rows mb, mb+16
  const int c4 = (t&15)*4;       // 4 consecutive c
  float acc[2][4] = {};
  for (int kt=0; kt<K_; kt+=16){
    {
      const int row = t>>3, kk = (t&7)*2;
      const float* ap = A + (size_t)(m0+row)*K_ + kt + kk;
      As[row][kk] = ap[0]; As[row][kk+1] = ap[1];
    }
    #pragma unroll
    for (int s2=0;s2<4;++s2){
      const int idx = t + 256*s2;
      const int r = idx>>6, cc = idx&63;
      Ws[r][cc] = W[(size_t)(kt+r)*HF_ + c0 + cc];
    }
    __syncthreads();
    #pragma unroll
    for (int k=0;k<16;++k){
      const float a0 = As[mb][k];
      const float a1 = As[mb+16][k];
      const float4 wv = *reinterpret_cast<const float4*>(&Ws[k][c4]);
      acc[0][0]=f_fma(a0,wv.x,acc[0][0]); acc[0][1]=f_fma(a0,wv.y,acc[0][1]);
      acc[0][2]=f_fma(a0,wv.z,acc[0][2]); acc[0][3]=f_fma(a0,wv.w,acc[0][3]);
      acc[1][0]=f_fma(a1,wv.x,acc[1][0]); acc[1][1]=f_fma(a1,wv.y,acc[1][1]);
      acc[1][2]=f_fma(a1,wv.z,acc[1][2]); acc[1][3]=f_fma(a1,wv.w,acc[1][3]);
    }
    __syncthreads();
  }
  #pragma unroll
  for (int q=0;q<2;++q){
    float4 o = make_float4(acc[q][0],acc[q][1],acc[q][2],acc[q][3]);
    *reinterpret_cast<float4*>(&C[(size_t)(m0+mb+16*q)*HF_ + c0 + c4]) = o;
  }
}

// ---- el/er: unchanged (sequential f ascending, mul+add separate) ----
__global__ __launch_bounds__(256) void eler_emu(const float* __restrict__ g, const float* __restrict__ a,
                                                float* __restrict__ el, float* __restrict__ er){
  const int gid = blockIdx.x*256 + threadIdx.x;   // (row, h)
  const int row = gid >> 3, h = gid & 7;
  const float* gr = g + (size_t)row*HF_ + h*64;
  float pl = 0.f, pr = 0.f;
  for (int f=0; f<64; ++f){
    pl = f_add(pl, f_mul(gr[f], a[f]));
    pr = f_add(pr, f_mul(gr[f], a[64+f]));
  }
  el[(size_t)row*NH_+h] = pl;
  er[(size_t)row*NH_+h] = pr;
}

// ---- attention, i-tiled: block per (bc, h, 16-row i-tile), 256 threads. FP identical. ----
__global__ __launch_bounds__(256) void att_tile(const float* __restrict__ g, const float* __restrict__ el,
                                                const float* __restrict__ er, const float* __restrict__ adjc,
                                                float* __restrict__ hout){
  const int bid = swz8(blockIdx.x, gridDim.x);
  const int it = bid & 31, h = (bid>>5)&7, bc = bid>>8;
  const int i0 = it*16;
  __shared__ float er_s[512];
  __shared__ float p_s[16][513];
  __shared__ float el_s[16];
  __shared__ float red[256];
  __shared__ float rs[16][33];
  __shared__ float m_s[16], den_s[16];
  const int t = threadIdx.x;
  if (t < 16) el_s[t] = el[((size_t)(bc*N_) + i0 + t)*NH_ + h];
  er_s[t]     = er[((size_t)(bc*N_) + t)*NH_ + h];
  er_s[t+256] = er[((size_t)(bc*N_) + t + 256)*NH_ + h];
  __syncthreads();
  // e (masked), all 16 rows
  for (int i=0;i<16;++i){
    const float eli = el_s[i];
    const int gi = i0 + i;
    #pragma unroll
    for (int s=0;s<2;++s){
      const int j = t + s*256;
      const float av = adjc[((size_t)(bc*N_)+gi)*N_ + j];
      const bool mask = (av != 0.f) || (gi == j);
      float e = lrelu_np(f_add(eli, er_s[j]));
      p_s[i][j] = mask ? e : -1000.0f;
    }
  }
  __syncthreads();
  // row max (order-free, exact)
  {
    const int i = t>>4, l = t&15;
    float mx = p_s[i][l];
    for (int u=1;u<32;++u) mx = fmaxf(mx, p_s[i][l + 16*u]);
    red[t] = mx;
  }
  __syncthreads();
  if (t < 128){ const int i=t>>3, l=t&7; red[i*16+l] = fmaxf(red[i*16+l], red[i*16+l+8]); }
  __syncthreads();
  if (t < 64){ const int i=t>>2, l=t&3; red[i*16+l] = fmaxf(red[i*16+l], red[i*16+l+4]); }
  __syncthreads();
  if (t < 32){ const int i=t>>1, l=t&1; red[i*16+l] = fmaxf(red[i*16+l], red[i*16+l+2]); }
  __syncthreads();
  if (t < 16) m_s[t] = fmaxf(red[t*16], red[t*16+1]);
  __syncthreads();
  // p = exp_cr(e - m)
  for (int i=0;i<16;++i){
    const float mi = m_s[i];
    #pragma unroll
    for (int s=0;s<2;++s){
      const int j = t + s*256;
      p_s[i][j] = expf_cr(f_sub(p_s[i][j], mi));
    }
  }
  __syncthreads();
  // den: numpy pairwise — slot (gq,l): r = seq sum_{m2} p[gq*128+m2*8+l]
  {
    const int i = t>>4;
    #pragma unroll
    for (int ss=0;ss<2;++ss){
      const int s = (t&15) + ss*16;
      const int gq = s>>3, l = s&7;
      float r = p_s[i][gq*128 + l];
      for (int m2=1;m2<16;++m2) r = f_add(r, p_s[i][gq*128 + m2*8 + l]);
      rs[i][s] = r;
    }
  }
  __syncthreads();
  if (t < 16){
    const int i = t;
    float pw[4];
    #pragma unroll
    for (int gq=0;gq<4;++gq){
      const float* rr = &rs[i][gq*8];
      pw[gq] = f_add(f_add(f_add(rr[0],rr[1]),f_add(rr[2],rr[3])),
                     f_add(f_add(rr[4],rr[5]),f_add(rr[6],rr[7])));
    }
    den_s[i] = f_add(f_add(pw[0],pw[1]), f_add(pw[2],pw[3]));
  }
  __syncthreads();
  // att = p/den
  for (int i=0;i<16;++i){
    const float di = den_s[i];
    #pragma unroll
    for (int s=0;s<2;++s){
      const int j = t + s*256;
      p_s[i][j] = f_div(p_s[i][j], di);
    }
  }
  __syncthreads();
  // aggregation: thread = (f = t&63, iw = t>>6); 4 chains; 1 g-load shared by 4 chains
  {
    const int f = t & 63, iw = t >> 6;
    float a0=0.f, a1=0.f, a2=0.f, a3=0.f;
    const float* gcol = g + (size_t)(bc*N_)*HF_ + h*64 + f;
    #pragma unroll 8
    for (int j=0;j<512;++j){
      const float gv = gcol[(size_t)j*HF_];
      a0 = f_add(a0, f_mul(p_s[iw   ][j], gv));
      a1 = f_add(a1, f_mul(p_s[iw+4 ][j], gv));
      a2 = f_add(a2, f_mul(p_s[iw+8 ][j], gv));
      a3 = f_add(a3, f_mul(p_s[iw+12][j], gv));
    }
    const size_t ob = (size_t)(bc*N_) + i0;
    hout[(ob+iw   )*HF_ + h*64 + f] = lrelu_np(a0);
    hout[(ob+iw+4 )*HF_ + h*64 + f] = lrelu_np(a1);
    hout[(ob+iw+8 )*HF_ + h*64 + f] = lrelu_np(a2);
    hout[(ob+iw+12)*HF_ + h*64 + f] = lrelu_np(a3);
  }
}

// ---- scores: unchanged (8-lane sgemv emulation + fixed tree + bp) ----
__global__ __launch_bounds__(256) void scores_emu(const float* __restrict__ h2, const float* __restrict__ Wp,
                                                  const float* __restrict__ bp, float* __restrict__ sc){
  const int r = blockIdx.x*256 + threadIdx.x;   // (bc, n)
  const float* hr = h2 + (size_t)r*HF_;
  float q0=0,q1=0,q2=0,q3=0,q4=0,q5=0,q6=0,q7=0;
  for (int k=0;k<512;k+=8){
    q0=f_fma(hr[k+0],Wp[k+0],q0); q1=f_fma(hr[k+1],Wp[k+1],q1);
    q2=f_fma(hr[k+2],Wp[k+2],q2); q3=f_fma(hr[k+3],Wp[k+3],q3);
    q4=f_fma(hr[k+4],Wp[k+4],q4); q5=f_fma(hr[k+5],Wp[k+5],q5);
    q6=f_fma(hr[k+6],Wp[k+6],q6); q7=f_fma(hr[k+7],Wp[k+7],q7);
  }
  const float d = f_add(f_add(f_add(q0,q4),f_add(q1,q5)), f_add(f_add(q2,q6),f_add(q3,q7)));
  sc[r] = f_add(d, bp[0]);
}

// ---- stable top-256 rank counting (unchanged) ----
__global__ __launch_bounds__(512) void topk_f(const float* __restrict__ sc, int* __restrict__ idx){
  __shared__ float sl[512];
  const int b = blockIdx.x, t = threadIdx.x;
  if (t < 256) idx[b*256+t] = t;
  sl[t] = sc[(size_t)b*N_+t];
  __syncthreads();
  const float mine = sl[t];
  int cnt = 0;
  for (int j=0;j<N_;++j){
    const float v = sl[j];
    cnt += (v > mine) || (v == mine && j < t);
  }
  if (cnt < 256) idx[b*256+cnt] = t;
}

__global__ __launch_bounds__(128) void gather_f(const float* __restrict__ h2, const int* __restrict__ idx,
                                                float* __restrict__ outc){
  const int r = blockIdx.x;
  const int bc = r>>8, kk = r&255;
  const int n = idx[bc*256+kk] & (N_-1);
  const int t = threadIdx.x;
  const float4 v = *reinterpret_cast<const float4*>(&h2[(size_t)(bc*N_+n)*HF_ + t*4]);
  *reinterpret_cast<float4*>(&outc[(size_t)(bc*256+kk)*HF_ + t*4]) = v;
}

extern "C" void kernel_launch(void* const* d_in, const int* in_sizes, int n_in,
                              void* d_out, int out_size, void* d_ws, size_t ws_size,
                              hipStream_t stream){
  const float* x   = (const float*)d_in[0];
  const float* adj = (const float*)d_in[1];
  const float* W1  = (const float*)d_in[2];
  const float* a1  = (const float*)d_in[3];
  const float* W2  = (const float*)d_in[4];
  const float* a2  = (const float*)d_in[5];
  const float* Wp  = (const float*)d_in[6];
  const float* bp  = (const float*)d_in[7];

  const size_t per = 3*1048576 + 2*16384 + 2048 + 1024;
  int C = B_;
  while (C > 1 && per*(size_t)C > ws_size) C >>= 1;

  char* w    = (char*)d_ws;
  float* g   = (float*)w;
  float* h1  = (float*)(w + (size_t)C*1048576);
  float* h2  = (float*)(w + (size_t)2*C*1048576);
  float* el  = (float*)(w + (size_t)3*C*1048576);
  float* er  = el + (size_t)C*4096;
  float* sc  = er + (size_t)C*4096;
  int*  idx  = (int*)(sc + (size_t)C*512);

  for (int b0 = 0; b0 < B_; b0 += C){
    const float* xc   = x   + (size_t)b0*N_*K_;
    const float* adjc = adj + (size_t)b0*N_*N_;
    float* outc = (float*)d_out + (size_t)b0*256*HF_;
    const int M = C*N_;
    dim3 gg(HF_/64, M/32);
    // layer 1
    gemm_t<<<gg, 256, 0, stream>>>(xc, W1, g);
    eler_emu<<<(M*NH_)/256, 256, 0, stream>>>(g, a1, el, er);
    att_tile<<<C*NH_*32, 256, 0, stream>>>(g, el, er, adjc, h1);
    // layer 2
    gemm_t<<<gg, 256, 0, stream>>>(h1, W2, g);
    eler_emu<<<(M*NH_)/256, 256, 0, stream>>>(g, a2, el, er);
    att_tile<<<C*NH_*32, 256, 0, stream>>>(g, el, er, adjc, h2);
    // pool
    scores_emu<<<M/256, 256, 0, stream>>>(h2, Wp, bp, sc);
    topk_f<<<C, 512, 0, stream>>>(sc, idx);
    gather_f<<<C*256, 128, 0, stream>>>(h2, idx, outc);
  }
}

// Round 12
// 371.779 us; speedup vs baseline: 4.6953x; 1.5245x over previous
//
#include <hip/hip_runtime.h>
#include <hip/hip_bf16.h>

#define B_  16
#define N_  512
#define K_  512
#define HF_ 512
#define NH_ 8

// ---- numpy f32 emulation helpers (explicit roundings; no contraction) ----
__device__ __forceinline__ float f_add(float a, float b){ return __fadd_rn(a,b); }
__device__ __forceinline__ float f_sub(float a, float b){ return __fsub_rn(a,b); }
__device__ __forceinline__ float f_mul(float a, float b){ return __fmul_rn(a,b); }
__device__ __forceinline__ float f_fma(float a, float b, float c){ return __fmaf_rn(a,b,c); }
__device__ __forceinline__ float f_div(float a, float b){ return __fdiv_rn(a,b); }
__device__ __forceinline__ float expf_cr(float x){ return (float)exp((double)x); }
__device__ __forceinline__ float lrelu_np(float x){ return x >= 0.f ? x : f_mul(0.1f, x); }

// XCD-aware chunked block swizzle (bijective when nwg%8==0 — true for all grids here).
__device__ __forceinline__ int swz8(int phys, int nwg){
  const int cpx = nwg >> 3;
  return (phys & 7)*cpx + (phys >> 3);
}

// ---- sgemm emu, 64x64 tile, BK=16. Per-element FP: sequential-k fused-FMA chain. ----
// 256 threads; thread = (mg = t>>4, cg = t&15) handles 4m x 4c = 16 chains.
__global__ __launch_bounds__(256) void gemm_t(const float* __restrict__ A, const float* __restrict__ W,
                                              float* __restrict__ C){
  __shared__ float As2[16][68];   // [k][m]
  __shared__ float Ws[16][68];    // [k][c]
  const int t  = threadIdx.x;
  const int nb = gridDim.x*gridDim.y;
  const int id = swz8(blockIdx.y*gridDim.x + blockIdx.x, nb);
  const int c0 = (id & 7)*64, m0 = (id >> 3)*64;
  const int mg = t>>4, cg = t&15;
  float acc[4][4] = {};
  for (int kt=0; kt<K_; kt+=16){
    {
      const int row = t>>2, kk4 = (t&3)*4;
      const float4 av = *reinterpret_cast<const float4*>(A + (size_t)(m0+row)*K_ + kt + kk4);
      As2[kk4+0][row]=av.x; As2[kk4+1][row]=av.y; As2[kk4+2][row]=av.z; As2[kk4+3][row]=av.w;
    }
    #pragma unroll
    for (int s2=0;s2<4;++s2){
      const int idx = t + 256*s2;
      const int r = idx>>6, cc = idx&63;
      Ws[r][cc] = W[(size_t)(kt+r)*HF_ + c0 + cc];
    }
    __syncthreads();
    #pragma unroll
    for (int k=0;k<16;++k){
      const float4 a4 = *reinterpret_cast<const float4*>(&As2[k][mg*4]);
      const float4 w4 = *reinterpret_cast<const float4*>(&Ws[k][cg*4]);
      acc[0][0]=f_fma(a4.x,w4.x,acc[0][0]); acc[0][1]=f_fma(a4.x,w4.y,acc[0][1]);
      acc[0][2]=f_fma(a4.x,w4.z,acc[0][2]); acc[0][3]=f_fma(a4.x,w4.w,acc[0][3]);
      acc[1][0]=f_fma(a4.y,w4.x,acc[1][0]); acc[1][1]=f_fma(a4.y,w4.y,acc[1][1]);
      acc[1][2]=f_fma(a4.y,w4.z,acc[1][2]); acc[1][3]=f_fma(a4.y,w4.w,acc[1][3]);
      acc[2][0]=f_fma(a4.z,w4.x,acc[2][0]); acc[2][1]=f_fma(a4.z,w4.y,acc[2][1]);
      acc[2][2]=f_fma(a4.z,w4.z,acc[2][2]); acc[2][3]=f_fma(a4.z,w4.w,acc[2][3]);
      acc[3][0]=f_fma(a4.w,w4.x,acc[3][0]); acc[3][1]=f_fma(a4.w,w4.y,acc[3][1]);
      acc[3][2]=f_fma(a4.w,w4.z,acc[3][2]); acc[3][3]=f_fma(a4.w,w4.w,acc[3][3]);
    }
    __syncthreads();
  }
  #pragma unroll
  for (int q=0;q<4;++q){
    float4 o = make_float4(acc[q][0],acc[q][1],acc[q][2],acc[q][3]);
    *reinterpret_cast<float4*>(&C[(size_t)(m0+mg*4+q)*HF_ + c0 + cg*4]) = o;
  }
}

// ---- el/er: unchanged (sequential f ascending, mul+add separate) ----
__global__ __launch_bounds__(256) void eler_emu(const float* __restrict__ g, const float* __restrict__ a,
                                                float* __restrict__ el, float* __restrict__ er){
  const int gid = blockIdx.x*256 + threadIdx.x;   // (row, h)
  const int row = gid >> 3, h = gid & 7;
  const float* gr = g + (size_t)row*HF_ + h*64;
  float pl = 0.f, pr = 0.f;
  for (int f=0; f<64; ++f){
    pl = f_add(pl, f_mul(gr[f], a[f]));
    pr = f_add(pr, f_mul(gr[f], a[64+f]));
  }
  el[(size_t)row*NH_+h] = pl;
  er[(size_t)row*NH_+h] = pr;
}

// ---- attention, i-tiled + SPARSE exp/div/agg (bitwise identical to dense; see proof in notes).
// masked slots hold sentinel -1000.0f; exp(masked)=+0.0f exactly; adding +-0 products is
// identity on the accumulator (it starts +0.0 and can never become -0.0). ----
__global__ __launch_bounds__(256) void att_tile(const float* __restrict__ g, const float* __restrict__ el,
                                                const float* __restrict__ er, const float* __restrict__ adjc,
                                                float* __restrict__ hout){
  const int bid = swz8(blockIdx.x, gridDim.x);
  const int it = bid & 31, h = (bid>>5)&7, bc = bid>>8;
  const int i0 = it*16;
  __shared__ float p_s[16][513];
  __shared__ float er_s[512];
  __shared__ float el_s[16];
  __shared__ float red[256];
  __shared__ float rs[16][33];
  __shared__ float m_s[16], den_s[16];
  __shared__ unsigned short list_s[16][128];
  __shared__ int cnt_s[16];
  const int t = threadIdx.x;
  if (t < 16) el_s[t] = el[((size_t)(bc*N_) + i0 + t)*NH_ + h];
  er_s[t]     = er[((size_t)(bc*N_) + t)*NH_ + h];
  er_s[t+256] = er[((size_t)(bc*N_) + t + 256)*NH_ + h];
  __syncthreads();
  // e (masked -> sentinel), all 16 rows
  for (int i=0;i<16;++i){
    const float eli = el_s[i];
    const int gi = i0 + i;
    #pragma unroll
    for (int s=0;s<2;++s){
      const int j = t + s*256;
      const float av = adjc[((size_t)(bc*N_)+gi)*N_ + j];
      const bool mask = (av != 0.f) || (gi == j);
      float e = lrelu_np(f_add(eli, er_s[j]));
      p_s[i][j] = mask ? e : -1000.0f;
    }
  }
  __syncthreads();
  // row max (order-free, exact; -1000 sentinels can't win: self-loop always present)
  {
    const int i = t>>4, l = t&15;
    float mx = p_s[i][l];
    for (int u=1;u<32;++u) mx = fmaxf(mx, p_s[i][l + 16*u]);
    red[t] = mx;
  }
  __syncthreads();
  if (t < 128){ const int i=t>>3, l=t&7; red[i*16+l] = fmaxf(red[i*16+l], red[i*16+l+8]); }
  __syncthreads();
  if (t < 64){ const int i=t>>2, l=t&3; red[i*16+l] = fmaxf(red[i*16+l], red[i*16+l+4]); }
  __syncthreads();
  if (t < 32){ const int i=t>>1, l=t&1; red[i*16+l] = fmaxf(red[i*16+l], red[i*16+l+2]); }
  __syncthreads();
  if (t < 16) m_s[t] = fmaxf(red[t*16], red[t*16+1]);
  __syncthreads();
  // neighbor-list build: wave wid handles rows wid*4..wid*4+3; ballot compaction, j ascending
  {
    const int wid = t>>6, lane = t&63;
    for (int r=0;r<4;++r){
      const int i = wid*4 + r;
      int cnt = 0;
      for (int cc=0; cc<8; ++cc){
        const int j = cc*64 + lane;
        const bool pred = (p_s[i][j] != -1000.0f);
        const unsigned long long mb = __ballot(pred);
        if (pred){
          const int pos = cnt + __popcll(mb & ((1ull<<lane)-1ull));
          if (pos < 128) list_s[i][pos] = (unsigned short)j;
        }
        cnt += (int)__popcll(mb);
      }
      if (lane == 0) cnt_s[i] = cnt;
    }
  }
  __syncthreads();
  // exp: sparse over list (dense fallback if row overflows cap)
  {
    const int i = t>>4, l = t&15;
    const float mi = m_s[i];
    const int cnt = cnt_s[i];
    if (cnt <= 128){
      for (int kk=l; kk<cnt; kk+=16){
        const int j = list_s[i][kk];
        p_s[i][j] = expf_cr(f_sub(p_s[i][j], mi));
      }
    } else {
      for (int j=l; j<512; j+=16){
        const float v = p_s[i][j];
        p_s[i][j] = (v == -1000.0f) ? 0.0f : expf_cr(f_sub(v, mi));
      }
    }
  }
  __syncthreads();
  // den: numpy pairwise (dense structure; sentinel reads as exactly +0.0f — same bits as before)
  {
    const int i = t>>4;
    #pragma unroll
    for (int ss=0;ss<2;++ss){
      const int s = (t&15) + ss*16;
      const int gq = s>>3, l = s&7;
      float v = p_s[i][gq*128 + l];
      float r = (v == -1000.0f) ? 0.0f : v;
      for (int m2=1;m2<16;++m2){
        v = p_s[i][gq*128 + m2*8 + l];
        r = f_add(r, (v == -1000.0f) ? 0.0f : v);
      }
      rs[i][s] = r;
    }
  }
  __syncthreads();
  if (t < 16){
    const int i = t;
    float pw[4];
    #pragma unroll
    for (int gq=0;gq<4;++gq){
      const float* rr = &rs[i][gq*8];
      pw[gq] = f_add(f_add(f_add(rr[0],rr[1]),f_add(rr[2],rr[3])),
                     f_add(f_add(rr[4],rr[5]),f_add(rr[6],rr[7])));
    }
    den_s[i] = f_add(f_add(pw[0],pw[1]), f_add(pw[2],pw[3]));
  }
  __syncthreads();
  // div: sparse over list (masked att never read downstream)
  {
    const int i = t>>4, l = t&15;
    const float di = den_s[i];
    const int cnt = cnt_s[i];
    if (cnt <= 128){
      for (int kk=l; kk<cnt; kk+=16){
        const int j = list_s[i][kk];
        p_s[i][j] = f_div(p_s[i][j], di);
      }
    } else {
      for (int j=l; j<512; j+=16) p_s[i][j] = f_div(p_s[i][j], di);
    }
  }
  __syncthreads();
  // aggregation: sparse j-ascending chain per (row, f); skipping +-0 products is bit-identity
  {
    const int f = t & 63, iw = t >> 6;
    const float* gcol = g + (size_t)(bc*N_)*HF_ + h*64 + f;
    const size_t ob = (size_t)(bc*N_) + i0;
    #pragma unroll
    for (int q=0;q<4;++q){
      const int i = iw + q*4;
      const int cnt = cnt_s[i];
      float a = 0.f;
      if (cnt <= 128){
        for (int kk=0; kk<cnt; ++kk){
          const int j = list_s[i][kk];
          a = f_add(a, f_mul(p_s[i][j], gcol[(size_t)j*HF_]));
        }
      } else {
        for (int j=0;j<512;++j)
          a = f_add(a, f_mul(p_s[i][j], gcol[(size_t)j*HF_]));
      }
      hout[(ob+i)*HF_ + h*64 + f] = lrelu_np(a);
    }
  }
}

// ---- scores: unchanged (8-lane sgemv emulation + fixed tree + bp) ----
__global__ __launch_bounds__(256) void scores_emu(const float* __restrict__ h2, const float* __restrict__ Wp,
                                                  const float* __restrict__ bp, float* __restrict__ sc){
  const int r = blockIdx.x*256 + threadIdx.x;   // (bc, n)
  const float* hr = h2 + (size_t)r*HF_;
  float q0=0,q1=0,q2=0,q3=0,q4=0,q5=0,q6=0,q7=0;
  for (int k=0;k<512;k+=8){
    q0=f_fma(hr[k+0],Wp[k+0],q0); q1=f_fma(hr[k+1],Wp[k+1],q1);
    q2=f_fma(hr[k+2],Wp[k+2],q2); q3=f_fma(hr[k+3],Wp[k+3],q3);
    q4=f_fma(hr[k+4],Wp[k+4],q4); q5=f_fma(hr[k+5],Wp[k+5],q5);
    q6=f_fma(hr[k+6],Wp[k+6],q6); q7=f_fma(hr[k+7],Wp[k+7],q7);
  }
  const float d = f_add(f_add(f_add(q0,q4),f_add(q1,q5)), f_add(f_add(q2,q6),f_add(q3,q7)));
  sc[r] = f_add(d, bp[0]);
}

// ---- stable top-256 rank counting (unchanged) ----
__global__ __launch_bounds__(512) void topk_f(const float* __restrict__ sc, int* __restrict__ idx){
  __shared__ float sl[512];
  const int b = blockIdx.x, t = threadIdx.x;
  if (t < 256) idx[b*256+t] = t;
  sl[t] = sc[(size_t)b*N_+t];
  __syncthreads();
  const float mine = sl[t];
  int cnt = 0;
  for (int j=0;j<N_;++j){
    const float v = sl[j];
    cnt += (v > mine) || (v == mine && j < t);
  }
  if (cnt < 256) idx[b*256+cnt] = t;
}

__global__ __launch_bounds__(128) void gather_f(const float* __restrict__ h2, const int* __restrict__ idx,
                                                float* __restrict__ outc){
  const int r = blockIdx.x;
  const int bc = r>>8, kk = r&255;
  const int n = idx[bc*256+kk] & (N_-1);
  const int t = threadIdx.x;
  const float4 v = *reinterpret_cast<const float4*>(&h2[(size_t)(bc*N_+n)*HF_ + t*4]);
  *reinterpret_cast<float4*>(&outc[(size_t)(bc*256+kk)*HF_ + t*4]) = v;
}

extern "C" void kernel_launch(void* const* d_in, const int* in_sizes, int n_in,
                              void* d_out, int out_size, void* d_ws, size_t ws_size,
                              hipStream_t stream){
  const float* x   = (const float*)d_in[0];
  const float* adj = (const float*)d_in[1];
  const float* W1  = (const float*)d_in[2];
  const float* a1  = (const float*)d_in[3];
  const float* W2  = (const float*)d_in[4];
  const float* a2  = (const float*)d_in[5];
  const float* Wp  = (const float*)d_in[6];
  const float* bp  = (const float*)d_in[7];

  const size_t per = 3*1048576 + 2*16384 + 2048 + 1024;
  int C = B_;
  while (C > 1 && per*(size_t)C > ws_size) C >>= 1;

  char* w    = (char*)d_ws;
  float* g   = (float*)w;
  float* h1  = (float*)(w + (size_t)C*1048576);
  float* h2  = (float*)(w + (size_t)2*C*1048576);
  float* el  = (float*)(w + (size_t)3*C*1048576);
  float* er  = el + (size_t)C*4096;
  float* sc  = er + (size_t)C*4096;
  int*  idx  = (int*)(sc + (size_t)C*512);

  for (int b0 = 0; b0 < B_; b0 += C){
    const float* xc   = x   + (size_t)b0*N_*K_;
    const float* adjc = adj + (size_t)b0*N_*N_;
    float* outc = (float*)d_out + (size_t)b0*256*HF_;
    const int M = C*N_;
    dim3 gg(HF_/64, M/64);
    // layer 1
    gemm_t<<<gg, 256, 0, stream>>>(xc, W1, g);
    eler_emu<<<(M*NH_)/256, 256, 0, stream>>>(g, a1, el, er);
    att_tile<<<C*NH_*32, 256, 0, stream>>>(g, el, er, adjc, h1);
    // layer 2
    gemm_t<<<gg, 256, 0, stream>>>(h1, W2, g);
    eler_emu<<<(M*NH_)/256, 256, 0, stream>>>(g, a2, el, er);
    att_tile<<<C*NH_*32, 256, 0, stream>>>(g, el, er, adjc, h2);
    // pool
    scores_emu<<<M/256, 256, 0, stream>>>(h2, Wp, bp, sc);
    topk_f<<<C, 512, 0, stream>>>(sc, idx);
    gather_f<<<C*256, 128, 0, stream>>>(h2, idx, outc);
  }
}

// Round 13
// 355.762 us; speedup vs baseline: 4.9067x; 1.0450x over previous
//
#include <hip/hip_runtime.h>
#include <hip/hip_bf16.h>

#define B_  16
#define N_  512
#define K_  512
#define HF_ 512
#define NH_ 8

// ---- numpy f32 emulation helpers (explicit roundings; no contraction) ----
__device__ __forceinline__ float f_add(float a, float b){ return __fadd_rn(a,b); }
__device__ __forceinline__ float f_sub(float a, float b){ return __fsub_rn(a,b); }
__device__ __forceinline__ float f_mul(float a, float b){ return __fmul_rn(a,b); }
__device__ __forceinline__ float f_fma(float a, float b, float c){ return __fmaf_rn(a,b,c); }
__device__ __forceinline__ float f_div(float a, float b){ return __fdiv_rn(a,b); }
__device__ __forceinline__ float expf_cr(float x){ return (float)exp((double)x); }
__device__ __forceinline__ float lrelu_np(float x){ return x >= 0.f ? x : f_mul(0.1f, x); }

// XCD-aware chunked block swizzle (bijective when nwg%8==0 — true for all grids here).
__device__ __forceinline__ int swz8(int phys, int nwg){
  const int cpx = nwg >> 3;
  return (phys & 7)*cpx + (phys >> 3);
}

// ---- sgemm emu, 64x64 tile, BK=16. Per-element FP: sequential-k fused-FMA chain. ----
__global__ __launch_bounds__(256) void gemm_t(const float* __restrict__ A, const float* __restrict__ W,
                                              float* __restrict__ C){
  __shared__ float As2[16][68];   // [k][m]
  __shared__ float Ws[16][68];    // [k][c]
  const int t  = threadIdx.x;
  const int nb = gridDim.x*gridDim.y;
  const int id = swz8(blockIdx.y*gridDim.x + blockIdx.x, nb);
  const int c0 = (id & 7)*64, m0 = (id >> 3)*64;
  const int mg = t>>4, cg = t&15;
  float acc[4][4] = {};
  for (int kt=0; kt<K_; kt+=16){
    {
      const int row = t>>2, kk4 = (t&3)*4;
      const float4 av = *reinterpret_cast<const float4*>(A + (size_t)(m0+row)*K_ + kt + kk4);
      As2[kk4+0][row]=av.x; As2[kk4+1][row]=av.y; As2[kk4+2][row]=av.z; As2[kk4+3][row]=av.w;
    }
    #pragma unroll
    for (int s2=0;s2<4;++s2){
      const int idx = t + 256*s2;
      const int r = idx>>6, cc = idx&63;
      Ws[r][cc] = W[(size_t)(kt+r)*HF_ + c0 + cc];
    }
    __syncthreads();
    #pragma unroll
    for (int k=0;k<16;++k){
      const float4 a4 = *reinterpret_cast<const float4*>(&As2[k][mg*4]);
      const float4 w4 = *reinterpret_cast<const float4*>(&Ws[k][cg*4]);
      acc[0][0]=f_fma(a4.x,w4.x,acc[0][0]); acc[0][1]=f_fma(a4.x,w4.y,acc[0][1]);
      acc[0][2]=f_fma(a4.x,w4.z,acc[0][2]); acc[0][3]=f_fma(a4.x,w4.w,acc[0][3]);
      acc[1][0]=f_fma(a4.y,w4.x,acc[1][0]); acc[1][1]=f_fma(a4.y,w4.y,acc[1][1]);
      acc[1][2]=f_fma(a4.y,w4.z,acc[1][2]); acc[1][3]=f_fma(a4.y,w4.w,acc[1][3]);
      acc[2][0]=f_fma(a4.z,w4.x,acc[2][0]); acc[2][1]=f_fma(a4.z,w4.y,acc[2][1]);
      acc[2][2]=f_fma(a4.z,w4.z,acc[2][2]); acc[2][3]=f_fma(a4.z,w4.w,acc[2][3]);
      acc[3][0]=f_fma(a4.w,w4.x,acc[3][0]); acc[3][1]=f_fma(a4.w,w4.y,acc[3][1]);
      acc[3][2]=f_fma(a4.w,w4.z,acc[3][2]); acc[3][3]=f_fma(a4.w,w4.w,acc[3][3]);
    }
    __syncthreads();
  }
  #pragma unroll
  for (int q=0;q<4;++q){
    float4 o = make_float4(acc[q][0],acc[q][1],acc[q][2],acc[q][3]);
    *reinterpret_cast<float4*>(&C[(size_t)(m0+mg*4+q)*HF_ + c0 + cg*4]) = o;
  }
}

// ---- el/er: unchanged (sequential f ascending, mul+add separate) ----
__global__ __launch_bounds__(256) void eler_emu(const float* __restrict__ g, const float* __restrict__ a,
                                                float* __restrict__ el, float* __restrict__ er){
  const int gid = blockIdx.x*256 + threadIdx.x;   // (row, h)
  const int row = gid >> 3, h = gid & 7;
  const float* gr = g + (size_t)row*HF_ + h*64;
  float pl = 0.f, pr = 0.f;
  for (int f=0; f<64; ++f){
    pl = f_add(pl, f_mul(gr[f], a[f]));
    pr = f_add(pr, f_mul(gr[f], a[64+f]));
  }
  el[(size_t)row*NH_+h] = pl;
  er[(size_t)row*NH_+h] = pr;
}

// ---- attention, fully sparse in list order (bitwise identical to dense numpy emulation).
// max over list == dense max (sentinels can't win; self-loop nonempty). den: numpy pairwise
// slot(j) = (j>>7)*8 + (j&7); masked slots are exact +0.0f -> skipping them is accumulator
// identity (all partials >= +0.0). agg: skipping +-0 products is identity (proven r12). ----
__global__ __launch_bounds__(256) void att_sp(const float* __restrict__ g, const float* __restrict__ el,
                                              const float* __restrict__ er, const float* __restrict__ adjc,
                                              float* __restrict__ hout){
  const int bid = swz8(blockIdx.x, gridDim.x);
  const int it = bid & 31, h = (bid>>5)&7, bc = bid>>8;
  const int i0 = it*16;
  __shared__ float er_s[512];
  __shared__ float el_s[16];
  __shared__ unsigned short list_s[16][128];
  __shared__ float pval_s[16][128];
  __shared__ int   cnt_s[16];
  __shared__ float m_s[16], den_s[16];
  __shared__ float rs[16][33];
  __shared__ float dense_s[513];   // overflow-fallback only
  __shared__ float red[256];       // overflow-fallback only
  const int t = threadIdx.x;
  if (t < 16) el_s[t] = el[((size_t)(bc*N_) + i0 + t)*NH_ + h];
  er_s[t]     = er[((size_t)(bc*N_) + t)*NH_ + h];
  er_s[t+256] = er[((size_t)(bc*N_) + t + 256)*NH_ + h];
  __syncthreads();
  // neighbor-list build from adj (ballot compaction, j ascending)
  {
    const int wid = t>>6, lane = t&63;
    for (int r=0;r<4;++r){
      const int i = wid*4 + r, gi = i0 + i;
      const float* arow = adjc + ((size_t)(bc*N_)+gi)*N_;
      int cnt = 0;
      for (int cc=0; cc<8; ++cc){
        const int j = cc*64 + lane;
        const bool pred = (arow[j] != 0.f) || (gi == j);
        const unsigned long long mb = __ballot(pred);
        if (pred){
          const int pos = cnt + __popcll(mb & ((1ull<<lane)-1ull));
          if (pos < 128) list_s[i][pos] = (unsigned short)j;
        }
        cnt += (int)__popcll(mb);
      }
      if (lane == 0) cnt_s[i] = cnt;
    }
  }
  __syncthreads();
  const int ir = t>>4, l = t&15;
  // e in list order + per-lane max
  {
    const int cnt = cnt_s[ir];
    const float eli = el_s[ir];
    float mx = -INFINITY;
    if (cnt <= 128){
      for (int kk=l; kk<cnt; kk+=16){
        const float e = lrelu_np(f_add(eli, er_s[list_s[ir][kk]]));
        pval_s[ir][kk] = e;
        mx = fmaxf(mx, e);
      }
    }
    rs[ir][l] = mx;
  }
  __syncthreads();
  if (t < 16){
    float m = rs[t][0];
    #pragma unroll
    for (int u=1;u<16;++u) m = fmaxf(m, rs[t][u]);
    m_s[t] = m;
  }
  __syncthreads();
  // exp over list
  {
    const int cnt = cnt_s[ir];
    const float mi = m_s[ir];
    if (cnt <= 128)
      for (int kk=l; kk<cnt; kk+=16)
        pval_s[ir][kk] = expf_cr(f_sub(pval_s[ir][kk], mi));
  }
  __syncthreads();
  // den: numpy pairwise via slot-sums (thread owns slots l and l+16 of row ir)
  {
    const int cnt = cnt_s[ir];
    if (cnt <= 128){
      #pragma unroll
      for (int ss=0; ss<2; ++ss){
        const int s = l + ss*16;
        float r = 0.f;
        for (int kk=0; kk<cnt; ++kk){
          const int j = list_s[ir][kk];
          const int slot = ((j>>7)<<3) | (j&7);
          if (slot == s) r = f_add(r, pval_s[ir][kk]);
        }
        rs[ir][s] = r;
      }
    }
  }
  __syncthreads();
  if (t < 16 && cnt_s[t] <= 128){
    float pw[4];
    #pragma unroll
    for (int gq=0;gq<4;++gq){
      const float* rr = &rs[t][gq*8];
      pw[gq] = f_add(f_add(f_add(rr[0],rr[1]),f_add(rr[2],rr[3])),
                     f_add(f_add(rr[4],rr[5]),f_add(rr[6],rr[7])));
    }
    den_s[t] = f_add(f_add(pw[0],pw[1]), f_add(pw[2],pw[3]));
  }
  __syncthreads();
  // div over list
  {
    const int cnt = cnt_s[ir];
    const float di = den_s[ir];
    if (cnt <= 128)
      for (int kk=l; kk<cnt; kk+=16)
        pval_s[ir][kk] = f_div(pval_s[ir][kk], di);
  }
  __syncthreads();
  // aggregation: sparse j-ascending chain per (row, f)
  {
    const int f = t & 63, iw = t >> 6;
    const float* gcol = g + (size_t)(bc*N_)*HF_ + h*64 + f;
    const size_t ob = (size_t)(bc*N_) + i0;
    #pragma unroll
    for (int q=0;q<4;++q){
      const int i = iw + q*4;
      const int cnt = cnt_s[i];
      if (cnt > 128) continue;
      float a = 0.f;
      for (int kk=0; kk<cnt; ++kk){
        const int j = list_s[i][kk];
        a = f_add(a, f_mul(pval_s[i][kk], gcol[(size_t)j*HF_]));
      }
      hout[(ob+i)*HF_ + h*64 + f] = lrelu_np(a);
    }
  }
  // dense fallback for overflow rows (cnt>128: structurally ~impossible, kept for correctness)
  for (int i=0;i<16;++i){
    if (cnt_s[i] <= 128) continue;     // cnt_s shared -> uniform branch
    __syncthreads();
    const int gi = i0 + i;
    const float eli = el_s[i];
    for (int s=0;s<2;++s){
      const int j = t + s*256;
      const float av = adjc[((size_t)(bc*N_)+gi)*N_ + j];
      const bool mask = (av != 0.f) || (gi == j);
      dense_s[j] = mask ? lrelu_np(f_add(eli, er_s[j])) : -1000.0f;
    }
    __syncthreads();
    red[t] = fmaxf(dense_s[t], dense_s[t+256]);
    __syncthreads();
    for (int s2=128; s2>=1; s2>>=1){ if (t<s2) red[t]=fmaxf(red[t],red[t+s2]); __syncthreads(); }
    const float mi = red[0];
    __syncthreads();
    for (int s=0;s<2;++s){
      const int j = t + s*256;
      const float v = dense_s[j];
      dense_s[j] = (v == -1000.0f) ? 0.0f : expf_cr(f_sub(v, mi));
    }
    __syncthreads();
    if (t < 32){
      const int gq = t>>3, ll = t&7;
      float r = dense_s[gq*128 + ll];
      for (int m2=1;m2<16;++m2) r = f_add(r, dense_s[gq*128 + m2*8 + ll]);
      rs[0][t] = r;
    }
    __syncthreads();
    if (t == 0){
      float pw[4];
      for (int gq=0;gq<4;++gq){
        const float* rr = &rs[0][gq*8];
        pw[gq] = f_add(f_add(f_add(rr[0],rr[1]),f_add(rr[2],rr[3])),
                       f_add(f_add(rr[4],rr[5]),f_add(rr[6],rr[7])));
      }
      den_s[0] = f_add(f_add(pw[0],pw[1]), f_add(pw[2],pw[3]));
    }
    __syncthreads();
    {
      const float di = den_s[0];
      for (int s=0;s<2;++s){ const int j=t+s*256; dense_s[j] = f_div(dense_s[j], di); }
    }
    __syncthreads();
    if (t < 64){
      const float* gcol = g + (size_t)(bc*N_)*HF_ + h*64 + t;
      float a = 0.f;
      for (int j=0;j<512;++j) a = f_add(a, f_mul(dense_s[j], gcol[(size_t)j*HF_]));
      hout[((size_t)(bc*N_)+gi)*HF_ + h*64 + t] = lrelu_np(a);
    }
  }
}

// ---- scores: unchanged (8-lane sgemv emulation + fixed tree + bp) ----
__global__ __launch_bounds__(256) void scores_emu(const float* __restrict__ h2, const float* __restrict__ Wp,
                                                  const float* __restrict__ bp, float* __restrict__ sc){
  const int r = blockIdx.x*256 + threadIdx.x;   // (bc, n)
  const float* hr = h2 + (size_t)r*HF_;
  float q0=0,q1=0,q2=0,q3=0,q4=0,q5=0,q6=0,q7=0;
  for (int k=0;k<512;k+=8){
    q0=f_fma(hr[k+0],Wp[k+0],q0); q1=f_fma(hr[k+1],Wp[k+1],q1);
    q2=f_fma(hr[k+2],Wp[k+2],q2); q3=f_fma(hr[k+3],Wp[k+3],q3);
    q4=f_fma(hr[k+4],Wp[k+4],q4); q5=f_fma(hr[k+5],Wp[k+5],q5);
    q6=f_fma(hr[k+6],Wp[k+6],q6); q7=f_fma(hr[k+7],Wp[k+7],q7);
  }
  const float d = f_add(f_add(f_add(q0,q4),f_add(q1,q5)), f_add(f_add(q2,q6),f_add(q3,q7)));
  sc[r] = f_add(d, bp[0]);
}

// ---- stable top-256 rank counting (unchanged) ----
__global__ __launch_bounds__(512) void topk_f(const float* __restrict__ sc, int* __restrict__ idx){
  __shared__ float sl[512];
  const int b = blockIdx.x, t = threadIdx.x;
  if (t < 256) idx[b*256+t] = t;
  sl[t] = sc[(size_t)b*N_+t];
  __syncthreads();
  const float mine = sl[t];
  int cnt = 0;
  for (int j=0;j<N_;++j){
    const float v = sl[j];
    cnt += (v > mine) || (v == mine && j < t);
  }
  if (cnt < 256) idx[b*256+cnt] = t;
}

__global__ __launch_bounds__(128) void gather_f(const float* __restrict__ h2, const int* __restrict__ idx,
                                                float* __restrict__ outc){
  const int r = blockIdx.x;
  const int bc = r>>8, kk = r&255;
  const int n = idx[bc*256+kk] & (N_-1);
  const int t = threadIdx.x;
  const float4 v = *reinterpret_cast<const float4*>(&h2[(size_t)(bc*N_+n)*HF_ + t*4]);
  *reinterpret_cast<float4*>(&outc[(size_t)(bc*256+kk)*HF_ + t*4]) = v;
}

extern "C" void kernel_launch(void* const* d_in, const int* in_sizes, int n_in,
                              void* d_out, int out_size, void* d_ws, size_t ws_size,
                              hipStream_t stream){
  const float* x   = (const float*)d_in[0];
  const float* adj = (const float*)d_in[1];
  const float* W1  = (const float*)d_in[2];
  const float* a1  = (const float*)d_in[3];
  const float* W2  = (const float*)d_in[4];
  const float* a2  = (const float*)d_in[5];
  const float* Wp  = (const float*)d_in[6];
  const float* bp  = (const float*)d_in[7];

  const size_t per = 3*1048576 + 2*16384 + 2048 + 1024;
  int C = B_;
  while (C > 1 && per*(size_t)C > ws_size) C >>= 1;

  char* w    = (char*)d_ws;
  float* g   = (float*)w;
  float* h1  = (float*)(w + (size_t)C*1048576);
  float* h2  = (float*)(w + (size_t)2*C*1048576);
  float* el  = (float*)(w + (size_t)3*C*1048576);
  float* er  = el + (size_t)C*4096;
  float* sc  = er + (size_t)C*4096;
  int*  idx  = (int*)(sc + (size_t)C*512);

  for (int b0 = 0; b0 < B_; b0 += C){
    const float* xc   = x   + (size_t)b0*N_*K_;
    const float* adjc = adj + (size_t)b0*N_*N_;
    float* outc = (float*)d_out + (size_t)b0*256*HF_;
    const int M = C*N_;
    dim3 gg(HF_/64, M/64);
    // layer 1
    gemm_t<<<gg, 256, 0, stream>>>(xc, W1, g);
    eler_emu<<<(M*NH_)/256, 256, 0, stream>>>(g, a1, el, er);
    att_sp<<<C*NH_*32, 256, 0, stream>>>(g, el, er, adjc, h1);
    // layer 2
    gemm_t<<<gg, 256, 0, stream>>>(h1, W2, g);
    eler_emu<<<(M*NH_)/256, 256, 0, stream>>>(g, a2, el, er);
    att_sp<<<C*NH_*32, 256, 0, stream>>>(g, el, er, adjc, h2);
    // pool
    scores_emu<<<M/256, 256, 0, stream>>>(h2, Wp, bp, sc);
    topk_f<<<C, 512, 0, stream>>>(sc, idx);
    gather_f<<<C*256, 128, 0, stream>>>(h2, idx, outc);
  }
}

// Round 17
// 346.191 us; speedup vs baseline: 5.0424x; 1.0276x over previous
//
#include <hip/hip_runtime.h>
#include <hip/hip_bf16.h>

#define B_  16
#define N_  512
#define K_  512
#define HF_ 512
#define NH_ 8

// ---- numpy f32 emulation helpers (explicit roundings; no contraction) ----
__device__ __forceinline__ float f_add(float a, float b){ return __fadd_rn(a,b); }
__device__ __forceinline__ float f_sub(float a, float b){ return __fsub_rn(a,b); }
__device__ __forceinline__ float f_mul(float a, float b){ return __fmul_rn(a,b); }
__device__ __forceinline__ float f_fma(float a, float b, float c){ return __fmaf_rn(a,b,c); }
__device__ __forceinline__ float f_div(float a, float b){ return __fdiv_rn(a,b); }
__device__ __forceinline__ float expf_cr(float x){ return (float)exp((double)x); }
__device__ __forceinline__ float lrelu_np(float x){ return x >= 0.f ? x : f_mul(0.1f, x); }

// XCD-aware chunked block swizzle (bijective when nwg%8==0 — true for all grids here).
__device__ __forceinline__ int swz8(int phys, int nwg){
  const int cpx = nwg >> 3;
  return (phys & 7)*cpx + (phys >> 3);
}

// ---- sgemm emu, 128x64 tile, BK=16. Per-element FP: sequential-k fused-FMA chain
// (identical 512-FMA k-ascending chain per output element as the passing 64x64 version). ----
__global__ __launch_bounds__(256) void gemm_t(const float* __restrict__ A, const float* __restrict__ W,
                                              float* __restrict__ C){
  __shared__ float As2[16][132];  // [k][m], m=128 (132: float4 reads stay 16B-aligned)
  __shared__ float Ws[16][68];    // [k][c]
  const int t  = threadIdx.x;
  const int nb = gridDim.x*gridDim.y;
  const int id = swz8(blockIdx.y*gridDim.x + blockIdx.x, nb);
  const int c0 = (id & 7)*64, m0 = (id >> 3)*128;
  const int mg = t>>4, cg = t&15;   // 8m x 4c per thread
  float acc[8][4] = {};
  for (int kt=0; kt<K_; kt+=16){
    {
      const int row = t>>1, kk4 = (t&1)*8;
      const float* ap = A + (size_t)(m0+row)*K_ + kt + kk4;
      const float4 av0 = *reinterpret_cast<const float4*>(ap);
      const float4 av1 = *reinterpret_cast<const float4*>(ap+4);
      As2[kk4+0][row]=av0.x; As2[kk4+1][row]=av0.y; As2[kk4+2][row]=av0.z; As2[kk4+3][row]=av0.w;
      As2[kk4+4][row]=av1.x; As2[kk4+5][row]=av1.y; As2[kk4+6][row]=av1.z; As2[kk4+7][row]=av1.w;
    }
    {
      const int r = t>>4, cc = (t&15)*4;
      const float4 wv = *reinterpret_cast<const float4*>(W + (size_t)(kt+r)*HF_ + c0 + cc);
      *reinterpret_cast<float4*>(&Ws[r][cc]) = wv;
    }
    __syncthreads();
    #pragma unroll
    for (int k=0;k<16;++k){
      const float4 a40 = *reinterpret_cast<const float4*>(&As2[k][mg*8]);
      const float4 a41 = *reinterpret_cast<const float4*>(&As2[k][mg*8+4]);
      const float4 w4  = *reinterpret_cast<const float4*>(&Ws[k][cg*4]);
      const float am[8] = {a40.x,a40.y,a40.z,a40.w,a41.x,a41.y,a41.z,a41.w};
      #pragma unroll
      for (int q=0;q<8;++q){
        acc[q][0]=f_fma(am[q],w4.x,acc[q][0]); acc[q][1]=f_fma(am[q],w4.y,acc[q][1]);
        acc[q][2]=f_fma(am[q],w4.z,acc[q][2]); acc[q][3]=f_fma(am[q],w4.w,acc[q][3]);
      }
    }
    __syncthreads();
  }
  #pragma unroll
  for (int q=0;q<8;++q){
    float4 o = make_float4(acc[q][0],acc[q][1],acc[q][2],acc[q][3]);
    *reinterpret_cast<float4*>(&C[(size_t)(m0+mg*8+q)*HF_ + c0 + cg*4]) = o;
  }
}

// ---- el/er: unchanged ----
__global__ __launch_bounds__(256) void eler_emu(const float* __restrict__ g, const float* __restrict__ a,
                                                float* __restrict__ el, float* __restrict__ er){
  const int gid = blockIdx.x*256 + threadIdx.x;   // (row, h)
  const int row = gid >> 3, h = gid & 7;
  const float* gr = g + (size_t)row*HF_ + h*64;
  float pl = 0.f, pr = 0.f;
  for (int f=0; f<64; ++f){
    pl = f_add(pl, f_mul(gr[f], a[f]));
    pr = f_add(pr, f_mul(gr[f], a[64+f]));
  }
  el[(size_t)row*NH_+h] = pl;
  er[(size_t)row*NH_+h] = pr;
}

// ---- attention: ROUND-13 VERBATIM (in-kernel ballot list build, scalar den/agg — known-pass). ----
__global__ __launch_bounds__(256) void att_sp(const float* __restrict__ g, const float* __restrict__ el,
                                              const float* __restrict__ er, const float* __restrict__ adjc,
                                              float* __restrict__ hout){
  const int bid = swz8(blockIdx.x, gridDim.x);
  const int it = bid & 31, h = (bid>>5)&7, bc = bid>>8;
  const int i0 = it*16;
  __shared__ float er_s[512];
  __shared__ float el_s[16];
  __shared__ unsigned short list_s[16][128];
  __shared__ float pval_s[16][128];
  __shared__ int   cnt_s[16];
  __shared__ float m_s[16], den_s[16];
  __shared__ float rs[16][33];
  __shared__ float dense_s[513];   // overflow-fallback only
  __shared__ float red[256];       // overflow-fallback only
  const int t = threadIdx.x;
  if (t < 16) el_s[t] = el[((size_t)(bc*N_) + i0 + t)*NH_ + h];
  er_s[t]     = er[((size_t)(bc*N_) + t)*NH_ + h];
  er_s[t+256] = er[((size_t)(bc*N_) + t + 256)*NH_ + h];
  __syncthreads();
  // neighbor-list build from adj (ballot compaction, j ascending)
  {
    const int wid = t>>6, lane = t&63;
    for (int r=0;r<4;++r){
      const int i = wid*4 + r, gi = i0 + i;
      const float* arow = adjc + ((size_t)(bc*N_)+gi)*N_;
      int cnt = 0;
      for (int cc=0; cc<8; ++cc){
        const int j = cc*64 + lane;
        const bool pred = (arow[j] != 0.f) || (gi == j);
        const unsigned long long mb = __ballot(pred);
        if (pred){
          const int pos = cnt + __popcll(mb & ((1ull<<lane)-1ull));
          if (pos < 128) list_s[i][pos] = (unsigned short)j;
        }
        cnt += (int)__popcll(mb);
      }
      if (lane == 0) cnt_s[i] = cnt;
    }
  }
  __syncthreads();
  const int ir = t>>4, l = t&15;
  // e in list order + per-lane max
  {
    const int cnt = cnt_s[ir];
    const float eli = el_s[ir];
    float mx = -INFINITY;
    if (cnt <= 128){
      for (int kk=l; kk<cnt; kk+=16){
        const float e = lrelu_np(f_add(eli, er_s[list_s[ir][kk]]));
        pval_s[ir][kk] = e;
        mx = fmaxf(mx, e);
      }
    }
    rs[ir][l] = mx;
  }
  __syncthreads();
  if (t < 16){
    float m = rs[t][0];
    #pragma unroll
    for (int u=1;u<16;++u) m = fmaxf(m, rs[t][u]);
    m_s[t] = m;
  }
  __syncthreads();
  // exp over list
  {
    const int cnt = cnt_s[ir];
    const float mi = m_s[ir];
    if (cnt <= 128)
      for (int kk=l; kk<cnt; kk+=16)
        pval_s[ir][kk] = expf_cr(f_sub(pval_s[ir][kk], mi));
  }
  __syncthreads();
  // den: numpy pairwise via slot-sums (thread owns slots l and l+16 of row ir) — SCALAR
  {
    const int cnt = cnt_s[ir];
    if (cnt <= 128){
      #pragma unroll
      for (int ss=0; ss<2; ++ss){
        const int s = l + ss*16;
        float r = 0.f;
        for (int kk=0; kk<cnt; ++kk){
          const int j = list_s[ir][kk];
          const int slot = ((j>>7)<<3) | (j&7);
          if (slot == s) r = f_add(r, pval_s[ir][kk]);
        }
        rs[ir][s] = r;
      }
    }
  }
  __syncthreads();
  if (t < 16 && cnt_s[t] <= 128){
    float pw[4];
    #pragma unroll
    for (int gq=0;gq<4;++gq){
      const float* rr = &rs[t][gq*8];
      pw[gq] = f_add(f_add(f_add(rr[0],rr[1]),f_add(rr[2],rr[3])),
                     f_add(f_add(rr[4],rr[5]),f_add(rr[6],rr[7])));
    }
    den_s[t] = f_add(f_add(pw[0],pw[1]), f_add(pw[2],pw[3]));
  }
  __syncthreads();
  // div over list
  {
    const int cnt = cnt_s[ir];
    const float di = den_s[ir];
    if (cnt <= 128)
      for (int kk=l; kk<cnt; kk+=16)
        pval_s[ir][kk] = f_div(pval_s[ir][kk], di);
  }
  __syncthreads();
  // aggregation: sparse j-ascending chain per (row, f) — SCALAR
  {
    const int f = t & 63, iw = t >> 6;
    const float* gcol = g + (size_t)(bc*N_)*HF_ + h*64 + f;
    const size_t ob = (size_t)(bc*N_) + i0;
    #pragma unroll
    for (int q=0;q<4;++q){
      const int i = iw + q*4;
      const int cnt = cnt_s[i];
      if (cnt > 128) continue;
      float a = 0.f;
      for (int kk=0; kk<cnt; ++kk){
        const int j = list_s[i][kk];
        a = f_add(a, f_mul(pval_s[i][kk], gcol[(size_t)j*HF_]));
      }
      hout[(ob+i)*HF_ + h*64 + f] = lrelu_np(a);
    }
  }
  // dense fallback for overflow rows (cnt>128; kept for unconditional correctness)
  for (int i=0;i<16;++i){
    if (cnt_s[i] <= 128) continue;
    __syncthreads();
    const int gi = i0 + i;
    const float eli = el_s[i];
    for (int s=0;s<2;++s){
      const int j = t + s*256;
      const float av = adjc[((size_t)(bc*N_)+gi)*N_ + j];
      const bool mask = (av != 0.f) || (gi == j);
      dense_s[j] = mask ? lrelu_np(f_add(eli, er_s[j])) : -1000.0f;
    }
    __syncthreads();
    red[t] = fmaxf(dense_s[t], dense_s[t+256]);
    __syncthreads();
    for (int s2=128; s2>=1; s2>>=1){ if (t<s2) red[t]=fmaxf(red[t],red[t+s2]); __syncthreads(); }
    const float mi = red[0];
    __syncthreads();
    for (int s=0;s<2;++s){
      const int j = t + s*256;
      const float v = dense_s[j];
      dense_s[j] = (v == -1000.0f) ? 0.0f : expf_cr(f_sub(v, mi));
    }
    __syncthreads();
    if (t < 32){
      const int gq = t>>3, ll = t&7;
      float r = dense_s[gq*128 + ll];
      for (int m2=1;m2<16;++m2) r = f_add(r, dense_s[gq*128 + m2*8 + ll]);
      rs[0][t] = r;
    }
    __syncthreads();
    if (t == 0){
      float pw[4];
      for (int gq=0;gq<4;++gq){
        const float* rr = &rs[0][gq*8];
        pw[gq] = f_add(f_add(f_add(rr[0],rr[1]),f_add(rr[2],rr[3])),
                       f_add(f_add(rr[4],rr[5]),f_add(rr[6],rr[7])));
      }
      den_s[0] = f_add(f_add(pw[0],pw[1]), f_add(pw[2],pw[3]));
    }
    __syncthreads();
    {
      const float di = den_s[0];
      for (int s=0;s<2;++s){ const int j=t+s*256; dense_s[j] = f_div(dense_s[j], di); }
    }
    __syncthreads();
    if (t < 64){
      const float* gcol = g + (size_t)(bc*N_)*HF_ + h*64 + t;
      float a = 0.f;
      for (int j=0;j<512;++j) a = f_add(a, f_mul(dense_s[j], gcol[(size_t)j*HF_]));
      hout[((size_t)(bc*N_)+gi)*HF_ + h*64 + t] = lrelu_np(a);
    }
  }
}

// ---- scores: unchanged ----
__global__ __launch_bounds__(256) void scores_emu(const float* __restrict__ h2, const float* __restrict__ Wp,
                                                  const float* __restrict__ bp, float* __restrict__ sc){
  const int r = blockIdx.x*256 + threadIdx.x;   // (bc, n)
  const float* hr = h2 + (size_t)r*HF_;
  float q0=0,q1=0,q2=0,q3=0,q4=0,q5=0,q6=0,q7=0;
  for (int k=0;k<512;k+=8){
    q0=f_fma(hr[k+0],Wp[k+0],q0); q1=f_fma(hr[k+1],Wp[k+1],q1);
    q2=f_fma(hr[k+2],Wp[k+2],q2); q3=f_fma(hr[k+3],Wp[k+3],q3);
    q4=f_fma(hr[k+4],Wp[k+4],q4); q5=f_fma(hr[k+5],Wp[k+5],q5);
    q6=f_fma(hr[k+6],Wp[k+6],q6); q7=f_fma(hr[k+7],Wp[k+7],q7);
  }
  const float d = f_add(f_add(f_add(q0,q4),f_add(q1,q5)), f_add(f_add(q2,q6),f_add(q3,q7)));
  sc[r] = f_add(d, bp[0]);
}

// ---- stable top-256 rank counting (unchanged) ----
__global__ __launch_bounds__(512) void topk_f(const float* __restrict__ sc, int* __restrict__ idx){
  __shared__ float sl[512];
  const int b = blockIdx.x, t = threadIdx.x;
  if (t < 256) idx[b*256+t] = t;
  sl[t] = sc[(size_t)b*N_+t];
  __syncthreads();
  const float mine = sl[t];
  int cnt = 0;
  for (int j=0;j<N_;++j){
    const float v = sl[j];
    cnt += (v > mine) || (v == mine && j < t);
  }
  if (cnt < 256) idx[b*256+cnt] = t;
}

__global__ __launch_bounds__(128) void gather_f(const float* __restrict__ h2, const int* __restrict__ idx,
                                                float* __restrict__ outc){
  const int r = blockIdx.x;
  const int bc = r>>8, kk = r&255;
  const int n = idx[bc*256+kk] & (N_-1);
  const int t = threadIdx.x;
  const float4 v = *reinterpret_cast<const float4*>(&h2[(size_t)(bc*N_+n)*HF_ + t*4]);
  *reinterpret_cast<float4*>(&outc[(size_t)(bc*256+kk)*HF_ + t*4]) = v;
}

extern "C" void kernel_launch(void* const* d_in, const int* in_sizes, int n_in,
                              void* d_out, int out_size, void* d_ws, size_t ws_size,
                              hipStream_t stream){
  const float* x   = (const float*)d_in[0];
  const float* adj = (const float*)d_in[1];
  const float* W1  = (const float*)d_in[2];
  const float* a1  = (const float*)d_in[3];
  const float* W2  = (const float*)d_in[4];
  const float* a2  = (const float*)d_in[5];
  const float* Wp  = (const float*)d_in[6];
  const float* bp  = (const float*)d_in[7];

  const size_t per = 3*1048576 + 2*16384 + 2048 + 1024;
  int C = B_;
  while (C > 1 && per*(size_t)C > ws_size) C >>= 1;

  char* w    = (char*)d_ws;
  float* g   = (float*)w;
  float* h1  = (float*)(w + (size_t)C*1048576);
  float* h2  = (float*)(w + (size_t)2*C*1048576);
  float* el  = (float*)(w + (size_t)3*C*1048576);
  float* er  = el + (size_t)C*4096;
  float* sc  = er + (size_t)C*4096;
  int*  idx  = (int*)(sc + (size_t)C*512);

  for (int b0 = 0; b0 < B_; b0 += C){
    const float* xc   = x   + (size_t)b0*N_*K_;
    const float* adjc = adj + (size_t)b0*N_*N_;
    float* outc = (float*)d_out + (size_t)b0*256*HF_;
    const int M = C*N_;
    dim3 gg(HF_/64, M/128);
    // layer 1
    gemm_t<<<gg, 256, 0, stream>>>(xc, W1, g);
    eler_emu<<<(M*NH_)/256, 256, 0, stream>>>(g, a1, el, er);
    att_sp<<<C*NH_*32, 256, 0, stream>>>(g, el, er, adjc, h1);
    // layer 2
    gemm_t<<<gg, 256, 0, stream>>>(h1, W2, g);
    eler_emu<<<(M*NH_)/256, 256, 0, stream>>>(g, a2, el, er);
    att_sp<<<C*NH_*32, 256, 0, stream>>>(g, el, er, adjc, h2);
    // pool
    scores_emu<<<M/256, 256, 0, stream>>>(h2, Wp, bp, sc);
    topk_f<<<C, 512, 0, stream>>>(sc, idx);
    gather_f<<<C*256, 128, 0, stream>>>(h2, idx, outc);
  }
}

// Round 18
// 299.374 us; speedup vs baseline: 5.8309x; 1.1564x over previous
//
#include <hip/hip_runtime.h>
#include <hip/hip_bf16.h>

#define B_  16
#define N_  512
#define K_  512
#define HF_ 512
#define NH_ 8

// ---- numpy f32 emulation helpers (explicit roundings; no contraction) ----
__device__ __forceinline__ float f_add(float a, float b){ return __fadd_rn(a,b); }
__device__ __forceinline__ float f_sub(float a, float b){ return __fsub_rn(a,b); }
__device__ __forceinline__ float f_mul(float a, float b){ return __fmul_rn(a,b); }
__device__ __forceinline__ float f_fma(float a, float b, float c){ return __fmaf_rn(a,b,c); }
__device__ __forceinline__ float f_div(float a, float b){ return __fdiv_rn(a,b); }
__device__ __forceinline__ float expf_cr(float x){ return (float)exp((double)x); }
__device__ __forceinline__ float lrelu_np(float x){ return x >= 0.f ? x : f_mul(0.1f, x); }

// XCD-aware chunked block swizzle (bijective when nwg%8==0 — true for all grids here).
__device__ __forceinline__ int swz8(int phys, int nwg){
  const int cpx = nwg >> 3;
  return (phys & 7)*cpx + (phys >> 3);
}

// ---- neighbor lists, built ONCE per chunk (adj is head- and layer-independent).
// wave per row; ascending-j ballot compaction — IDENTICAL order to the in-kernel build.
__global__ __launch_bounds__(256) void build_lists(const float* __restrict__ adjc,
                                                   unsigned short* __restrict__ lists,
                                                   int* __restrict__ cnts){
  const int w = (blockIdx.x*256 + threadIdx.x) >> 6;
  const int lane = threadIdx.x & 63;
  const int bc = w >> 9, gi = w & 511;
  const float* arow = adjc + ((size_t)(bc*N_)+gi)*N_;
  unsigned short* lp = lists + ((size_t)(bc*N_)+gi)*128;
  int cnt = 0;
  for (int cc=0; cc<8; ++cc){
    const int j = cc*64 + lane;
    const bool pred = (arow[j] != 0.f) || (gi == j);
    const unsigned long long mb = __ballot(pred);
    if (pred){
      const int pos = cnt + __popcll(mb & ((1ull<<lane)-1ull));
      if (pos < 128) lp[pos] = (unsigned short)j;
    }
    cnt += (int)__popcll(mb);
  }
  if (lane == 0) cnts[bc*N_+gi] = cnt;
}

// ---- sgemm emu, 128x64 tile, BK=16 — VERBATIM round 17 (known-pass). ----
__global__ __launch_bounds__(256) void gemm_t(const float* __restrict__ A, const float* __restrict__ W,
                                              float* __restrict__ C){
  __shared__ float As2[16][132];  // [k][m], m=128
  __shared__ float Ws[16][68];    // [k][c]
  const int t  = threadIdx.x;
  const int nb = gridDim.x*gridDim.y;
  const int id = swz8(blockIdx.y*gridDim.x + blockIdx.x, nb);
  const int c0 = (id & 7)*64, m0 = (id >> 3)*128;
  const int mg = t>>4, cg = t&15;   // 8m x 4c per thread
  float acc[8][4] = {};
  for (int kt=0; kt<K_; kt+=16){
    {
      const int row = t>>1, kk4 = (t&1)*8;
      const float* ap = A + (size_t)(m0+row)*K_ + kt + kk4;
      const float4 av0 = *reinterpret_cast<const float4*>(ap);
      const float4 av1 = *reinterpret_cast<const float4*>(ap+4);
      As2[kk4+0][row]=av0.x; As2[kk4+1][row]=av0.y; As2[kk4+2][row]=av0.z; As2[kk4+3][row]=av0.w;
      As2[kk4+4][row]=av1.x; As2[kk4+5][row]=av1.y; As2[kk4+6][row]=av1.z; As2[kk4+7][row]=av1.w;
    }
    {
      const int r = t>>4, cc = (t&15)*4;
      const float4 wv = *reinterpret_cast<const float4*>(W + (size_t)(kt+r)*HF_ + c0 + cc);
      *reinterpret_cast<float4*>(&Ws[r][cc]) = wv;
    }
    __syncthreads();
    #pragma unroll
    for (int k=0;k<16;++k){
      const float4 a40 = *reinterpret_cast<const float4*>(&As2[k][mg*8]);
      const float4 a41 = *reinterpret_cast<const float4*>(&As2[k][mg*8+4]);
      const float4 w4  = *reinterpret_cast<const float4*>(&Ws[k][cg*4]);
      const float am[8] = {a40.x,a40.y,a40.z,a40.w,a41.x,a41.y,a41.z,a41.w};
      #pragma unroll
      for (int q=0;q<8;++q){
        acc[q][0]=f_fma(am[q],w4.x,acc[q][0]); acc[q][1]=f_fma(am[q],w4.y,acc[q][1]);
        acc[q][2]=f_fma(am[q],w4.z,acc[q][2]); acc[q][3]=f_fma(am[q],w4.w,acc[q][3]);
      }
    }
    __syncthreads();
  }
  #pragma unroll
  for (int q=0;q<8;++q){
    float4 o = make_float4(acc[q][0],acc[q][1],acc[q][2],acc[q][3]);
    *reinterpret_cast<float4*>(&C[(size_t)(m0+mg*8+q)*HF_ + c0 + cg*4]) = o;
  }
}

// ---- el/er: unchanged ----
__global__ __launch_bounds__(256) void eler_emu(const float* __restrict__ g, const float* __restrict__ a,
                                                float* __restrict__ el, float* __restrict__ er){
  const int gid = blockIdx.x*256 + threadIdx.x;   // (row, h)
  const int row = gid >> 3, h = gid & 7;
  const float* gr = g + (size_t)row*HF_ + h*64;
  float pl = 0.f, pr = 0.f;
  for (int f=0; f<64; ++f){
    pl = f_add(pl, f_mul(gr[f], a[f]));
    pr = f_add(pr, f_mul(gr[f], a[64+f]));
  }
  el[(size_t)row*NH_+h] = pl;
  er[(size_t)row*NH_+h] = pr;
}

// ---- attention: r17 VERBATIM except lists/cnts come precomputed; staged with SCALAR
// ushort LDS stores (NO vector-typed LDS accesses — the convicted poison class). ----
__global__ __launch_bounds__(256) void att_sp(const float* __restrict__ g, const float* __restrict__ el,
                                              const float* __restrict__ er, const float* __restrict__ adjc,
                                              const unsigned short* __restrict__ lists,
                                              const int* __restrict__ cnts,
                                              float* __restrict__ hout){
  const int bid = swz8(blockIdx.x, gridDim.x);
  const int it = bid & 31, h = (bid>>5)&7, bc = bid>>8;
  const int i0 = it*16;
  __shared__ float er_s[512];
  __shared__ float el_s[16];
  __shared__ unsigned short list_s[16][128];
  __shared__ float pval_s[16][128];
  __shared__ int   cnt_s[16];
  __shared__ float m_s[16], den_s[16];
  __shared__ float rs[16][33];
  __shared__ float dense_s[513];   // overflow-fallback only
  __shared__ float red[256];       // overflow-fallback only
  const int t = threadIdx.x;
  if (t < 16){ el_s[t] = el[((size_t)(bc*N_) + i0 + t)*NH_ + h]; cnt_s[t] = cnts[bc*N_+i0+t]; }
  er_s[t]     = er[((size_t)(bc*N_) + t)*NH_ + h];
  er_s[t+256] = er[((size_t)(bc*N_) + t + 256)*NH_ + h];
  // stage lists: row r = t>>4, lane l = t&15 copies 8 consecutive entries — ALL SCALAR
  {
    const int r = t>>4, off = (t&15)*8;
    const unsigned short* lp = lists + ((size_t)(bc*N_)+i0+r)*128 + off;
    #pragma unroll
    for (int q=0;q<8;++q) list_s[r][off+q] = lp[q];
  }
  __syncthreads();
  const int ir = t>>4, l = t&15;
  // e in list order + per-lane max
  {
    const int cnt = cnt_s[ir];
    const float eli = el_s[ir];
    float mx = -INFINITY;
    if (cnt <= 128){
      for (int kk=l; kk<cnt; kk+=16){
        const float e = lrelu_np(f_add(eli, er_s[list_s[ir][kk]]));
        pval_s[ir][kk] = e;
        mx = fmaxf(mx, e);
      }
    }
    rs[ir][l] = mx;
  }
  __syncthreads();
  if (t < 16){
    float m = rs[t][0];
    #pragma unroll
    for (int u=1;u<16;++u) m = fmaxf(m, rs[t][u]);
    m_s[t] = m;
  }
  __syncthreads();
  // exp over list
  {
    const int cnt = cnt_s[ir];
    const float mi = m_s[ir];
    if (cnt <= 128)
      for (int kk=l; kk<cnt; kk+=16)
        pval_s[ir][kk] = expf_cr(f_sub(pval_s[ir][kk], mi));
  }
  __syncthreads();
  // den: numpy pairwise via slot-sums (thread owns slots l and l+16 of row ir) — SCALAR
  {
    const int cnt = cnt_s[ir];
    if (cnt <= 128){
      #pragma unroll
      for (int ss=0; ss<2; ++ss){
        const int s = l + ss*16;
        float r = 0.f;
        for (int kk=0; kk<cnt; ++kk){
          const int j = list_s[ir][kk];
          const int slot = ((j>>7)<<3) | (j&7);
          if (slot == s) r = f_add(r, pval_s[ir][kk]);
        }
        rs[ir][s] = r;
      }
    }
  }
  __syncthreads();
  if (t < 16 && cnt_s[t] <= 128){
    float pw[4];
    #pragma unroll
    for (int gq=0;gq<4;++gq){
      const float* rr = &rs[t][gq*8];
      pw[gq] = f_add(f_add(f_add(rr[0],rr[1]),f_add(rr[2],rr[3])),
                     f_add(f_add(rr[4],rr[5]),f_add(rr[6],rr[7])));
    }
    den_s[t] = f_add(f_add(pw[0],pw[1]), f_add(pw[2],pw[3]));
  }
  __syncthreads();
  // div over list
  {
    const int cnt = cnt_s[ir];
    const float di = den_s[ir];
    if (cnt <= 128)
      for (int kk=l; kk<cnt; kk+=16)
        pval_s[ir][kk] = f_div(pval_s[ir][kk], di);
  }
  __syncthreads();
  // aggregation: sparse j-ascending chain per (row, f) — SCALAR
  {
    const int f = t & 63, iw = t >> 6;
    const float* gcol = g + (size_t)(bc*N_)*HF_ + h*64 + f;
    const size_t ob = (size_t)(bc*N_) + i0;
    #pragma unroll
    for (int q=0;q<4;++q){
      const int i = iw + q*4;
      const int cnt = cnt_s[i];
      if (cnt > 128) continue;
      float a = 0.f;
      for (int kk=0; kk<cnt; ++kk){
        const int j = list_s[i][kk];
        a = f_add(a, f_mul(pval_s[i][kk], gcol[(size_t)j*HF_]));
      }
      hout[(ob+i)*HF_ + h*64 + f] = lrelu_np(a);
    }
  }
  // dense fallback for overflow rows (cnt>128; kept for unconditional correctness)
  for (int i=0;i<16;++i){
    if (cnt_s[i] <= 128) continue;
    __syncthreads();
    const int gi = i0 + i;
    const float eli = el_s[i];
    for (int s=0;s<2;++s){
      const int j = t + s*256;
      const float av = adjc[((size_t)(bc*N_)+gi)*N_ + j];
      const bool mask = (av != 0.f) || (gi == j);
      dense_s[j] = mask ? lrelu_np(f_add(eli, er_s[j])) : -1000.0f;
    }
    __syncthreads();
    red[t] = fmaxf(dense_s[t], dense_s[t+256]);
    __syncthreads();
    for (int s2=128; s2>=1; s2>>=1){ if (t<s2) red[t]=fmaxf(red[t],red[t+s2]); __syncthreads(); }
    const float mi = red[0];
    __syncthreads();
    for (int s=0;s<2;++s){
      const int j = t + s*256;
      const float v = dense_s[j];
      dense_s[j] = (v == -1000.0f) ? 0.0f : expf_cr(f_sub(v, mi));
    }
    __syncthreads();
    if (t < 32){
      const int gq = t>>3, ll = t&7;
      float r = dense_s[gq*128 + ll];
      for (int m2=1;m2<16;++m2) r = f_add(r, dense_s[gq*128 + m2*8 + ll]);
      rs[0][t] = r;
    }
    __syncthreads();
    if (t == 0){
      float pw[4];
      for (int gq=0;gq<4;++gq){
        const float* rr = &rs[0][gq*8];
        pw[gq] = f_add(f_add(f_add(rr[0],rr[1]),f_add(rr[2],rr[3])),
                       f_add(f_add(rr[4],rr[5]),f_add(rr[6],rr[7])));
      }
      den_s[0] = f_add(f_add(pw[0],pw[1]), f_add(pw[2],pw[3]));
    }
    __syncthreads();
    {
      const float di = den_s[0];
      for (int s=0;s<2;++s){ const int j=t+s*256; dense_s[j] = f_div(dense_s[j], di); }
    }
    __syncthreads();
    if (t < 64){
      const float* gcol = g + (size_t)(bc*N_)*HF_ + h*64 + t;
      float a = 0.f;
      for (int j=0;j<512;++j) a = f_add(a, f_mul(dense_s[j], gcol[(size_t)j*HF_]));
      hout[((size_t)(bc*N_)+gi)*HF_ + h*64 + t] = lrelu_np(a);
    }
  }
}

// ---- scores: unchanged ----
__global__ __launch_bounds__(256) void scores_emu(const float* __restrict__ h2, const float* __restrict__ Wp,
                                                  const float* __restrict__ bp, float* __restrict__ sc){
  const int r = blockIdx.x*256 + threadIdx.x;   // (bc, n)
  const float* hr = h2 + (size_t)r*HF_;
  float q0=0,q1=0,q2=0,q3=0,q4=0,q5=0,q6=0,q7=0;
  for (int k=0;k<512;k+=8){
    q0=f_fma(hr[k+0],Wp[k+0],q0); q1=f_fma(hr[k+1],Wp[k+1],q1);
    q2=f_fma(hr[k+2],Wp[k+2],q2); q3=f_fma(hr[k+3],Wp[k+3],q3);
    q4=f_fma(hr[k+4],Wp[k+4],q4); q5=f_fma(hr[k+5],Wp[k+5],q5);
    q6=f_fma(hr[k+6],Wp[k+6],q6); q7=f_fma(hr[k+7],Wp[k+7],q7);
  }
  const float d = f_add(f_add(f_add(q0,q4),f_add(q1,q5)), f_add(f_add(q2,q6),f_add(q3,q7)));
  sc[r] = f_add(d, bp[0]);
}

// ---- stable top-256 rank counting (unchanged) ----
__global__ __launch_bounds__(512) void topk_f(const float* __restrict__ sc, int* __restrict__ idx){
  __shared__ float sl[512];
  const int b = blockIdx.x, t = threadIdx.x;
  if (t < 256) idx[b*256+t] = t;
  sl[t] = sc[(size_t)b*N_+t];
  __syncthreads();
  const float mine = sl[t];
  int cnt = 0;
  for (int j=0;j<N_;++j){
    const float v = sl[j];
    cnt += (v > mine) || (v == mine && j < t);
  }
  if (cnt < 256) idx[b*256+cnt] = t;
}

__global__ __launch_bounds__(128) void gather_f(const float* __restrict__ h2, const int* __restrict__ idx,
                                                float* __restrict__ outc){
  const int r = blockIdx.x;
  const int bc = r>>8, kk = r&255;
  const int n = idx[bc*256+kk] & (N_-1);
  const int t = threadIdx.x;
  const float4 v = *reinterpret_cast<const float4*>(&h2[(size_t)(bc*N_+n)*HF_ + t*4]);
  *reinterpret_cast<float4*>(&outc[(size_t)(bc*256+kk)*HF_ + t*4]) = v;
}

extern "C" void kernel_launch(void* const* d_in, const int* in_sizes, int n_in,
                              void* d_out, int out_size, void* d_ws, size_t ws_size,
                              hipStream_t stream){
  const float* x   = (const float*)d_in[0];
  const float* adj = (const float*)d_in[1];
  const float* W1  = (const float*)d_in[2];
  const float* a1  = (const float*)d_in[3];
  const float* W2  = (const float*)d_in[4];
  const float* a2  = (const float*)d_in[5];
  const float* Wp  = (const float*)d_in[6];
  const float* bp  = (const float*)d_in[7];

  // per-batch: g/h1/h2 1MiB each + el/er 16KiB + sc 2KiB + idx 1KiB + lists 128KiB + cnts 2KiB
  const size_t per = 3314688;
  int C = B_;
  while (C > 1 && per*(size_t)C > ws_size) C >>= 1;

  char* w    = (char*)d_ws;
  float* g   = (float*)w;
  float* h1  = (float*)(w + (size_t)C*1048576);
  float* h2  = (float*)(w + (size_t)2*C*1048576);
  float* el  = (float*)(w + (size_t)3*C*1048576);
  float* er  = el + (size_t)C*4096;
  float* sc  = er + (size_t)C*4096;
  int*  idx  = (int*)(sc + (size_t)C*512);
  unsigned short* lists = (unsigned short*)((char*)idx + (size_t)C*1024);
  int*  cnts = (int*)((char*)lists + (size_t)C*131072);

  for (int b0 = 0; b0 < B_; b0 += C){
    const float* xc   = x   + (size_t)b0*N_*K_;
    const float* adjc = adj + (size_t)b0*N_*N_;
    float* outc = (float*)d_out + (size_t)b0*256*HF_;
    const int M = C*N_;
    dim3 gg(HF_/64, M/128);
    build_lists<<<C*128, 256, 0, stream>>>(adjc, lists, cnts);
    // layer 1
    gemm_t<<<gg, 256, 0, stream>>>(xc, W1, g);
    eler_emu<<<(M*NH_)/256, 256, 0, stream>>>(g, a1, el, er);
    att_sp<<<C*NH_*32, 256, 0, stream>>>(g, el, er, adjc, lists, cnts, h1);
    // layer 2
    gemm_t<<<gg, 256, 0, stream>>>(h1, W2, g);
    eler_emu<<<(M*NH_)/256, 256, 0, stream>>>(g, a2, el, er);
    att_sp<<<C*NH_*32, 256, 0, stream>>>(g, el, er, adjc, lists, cnts, h2);
    // pool
    scores_emu<<<M/256, 256, 0, stream>>>(h2, Wp, bp, sc);
    topk_f<<<C, 512, 0, stream>>>(sc, idx);
    gather_f<<<C*256, 128, 0, stream>>>(h2, idx, outc);
  }
}

// Round 19
// 294.308 us; speedup vs baseline: 5.9313x; 1.0172x over previous
//
#include <hip/hip_runtime.h>
#include <hip/hip_bf16.h>

#define B_  16
#define N_  512
#define K_  512
#define HF_ 512
#define NH_ 8

// ---- numpy f32 emulation helpers (explicit roundings; no contraction) ----
__device__ __forceinline__ float f_add(float a, float b){ return __fadd_rn(a,b); }
__device__ __forceinline__ float f_sub(float a, float b){ return __fsub_rn(a,b); }
__device__ __forceinline__ float f_mul(float a, float b){ return __fmul_rn(a,b); }
__device__ __forceinline__ float f_fma(float a, float b, float c){ return __fmaf_rn(a,b,c); }
__device__ __forceinline__ float f_div(float a, float b){ return __fdiv_rn(a,b); }
__device__ __forceinline__ float expf_cr(float x){ return (float)exp((double)x); }
__device__ __forceinline__ float lrelu_np(float x){ return x >= 0.f ? x : f_mul(0.1f, x); }

// XCD-aware chunked block swizzle (bijective when nwg%8==0 — true for all grids here).
__device__ __forceinline__ int swz8(int phys, int nwg){
  const int cpx = nwg >> 3;
  return (phys & 7)*cpx + (phys >> 3);
}

// ---- neighbor lists, built ONCE per chunk — VERBATIM round 18 (known-pass). ----
__global__ __launch_bounds__(256) void build_lists(const float* __restrict__ adjc,
                                                   unsigned short* __restrict__ lists,
                                                   int* __restrict__ cnts){
  const int w = (blockIdx.x*256 + threadIdx.x) >> 6;
  const int lane = threadIdx.x & 63;
  const int bc = w >> 9, gi = w & 511;
  const float* arow = adjc + ((size_t)(bc*N_)+gi)*N_;
  unsigned short* lp = lists + ((size_t)(bc*N_)+gi)*128;
  int cnt = 0;
  for (int cc=0; cc<8; ++cc){
    const int j = cc*64 + lane;
    const bool pred = (arow[j] != 0.f) || (gi == j);
    const unsigned long long mb = __ballot(pred);
    if (pred){
      const int pos = cnt + __popcll(mb & ((1ull<<lane)-1ull));
      if (pos < 128) lp[pos] = (unsigned short)j;
    }
    cnt += (int)__popcll(mb);
  }
  if (lane == 0) cnts[bc*N_+gi] = cnt;
}

// ---- sgemm emu, 128x64 tile, BK=16, REGISTER-BUFFERED PIPELINE.
// Per-element FP: the identical sequential-k 512-FMA chain; only staging timing changes. ----
__global__ __launch_bounds__(256) void gemm_t(const float* __restrict__ A, const float* __restrict__ W,
                                              float* __restrict__ C){
  __shared__ float As2[16][132];  // [k][m], m=128
  __shared__ float Ws[16][68];    // [k][c]
  const int t  = threadIdx.x;
  const int nb = gridDim.x*gridDim.y;
  const int id = swz8(blockIdx.y*gridDim.x + blockIdx.x, nb);
  const int c0 = (id & 7)*64, m0 = (id >> 3)*128;
  const int mg = t>>4, cg = t&15;   // 8m x 4c per thread
  const int arow = t>>1, akk = (t&1)*8;   // A stage: row, 8 k
  const int wr = t>>4, wcc = (t&15)*4;    // W stage: k row, 4 c
  float4 av0, av1, wv;
  {
    const float* ap = A + (size_t)(m0+arow)*K_ + akk;
    av0 = *reinterpret_cast<const float4*>(ap);
    av1 = *reinterpret_cast<const float4*>(ap+4);
    wv  = *reinterpret_cast<const float4*>(W + (size_t)wr*HF_ + c0 + wcc);
  }
  float acc[8][4] = {};
  for (int kt=0; kt<K_; kt+=16){
    __syncthreads();   // previous compute done reading LDS
    As2[akk+0][arow]=av0.x; As2[akk+1][arow]=av0.y; As2[akk+2][arow]=av0.z; As2[akk+3][arow]=av0.w;
    As2[akk+4][arow]=av1.x; As2[akk+5][arow]=av1.y; As2[akk+6][arow]=av1.z; As2[akk+7][arow]=av1.w;
    *reinterpret_cast<float4*>(&Ws[wr][wcc]) = wv;
    __syncthreads();
    if (kt+16 < K_){   // prefetch next K-step; latency hides under compute below
      const float* ap = A + (size_t)(m0+arow)*K_ + kt + 16 + akk;
      av0 = *reinterpret_cast<const float4*>(ap);
      av1 = *reinterpret_cast<const float4*>(ap+4);
      wv  = *reinterpret_cast<const float4*>(W + (size_t)(kt+16+wr)*HF_ + c0 + wcc);
    }
    #pragma unroll
    for (int k=0;k<16;++k){
      const float4 a40 = *reinterpret_cast<const float4*>(&As2[k][mg*8]);
      const float4 a41 = *reinterpret_cast<const float4*>(&As2[k][mg*8+4]);
      const float4 w4  = *reinterpret_cast<const float4*>(&Ws[k][cg*4]);
      const float am[8] = {a40.x,a40.y,a40.z,a40.w,a41.x,a41.y,a41.z,a41.w};
      #pragma unroll
      for (int q=0;q<8;++q){
        acc[q][0]=f_fma(am[q],w4.x,acc[q][0]); acc[q][1]=f_fma(am[q],w4.y,acc[q][1]);
        acc[q][2]=f_fma(am[q],w4.z,acc[q][2]); acc[q][3]=f_fma(am[q],w4.w,acc[q][3]);
      }
    }
  }
  #pragma unroll
  for (int q=0;q<8;++q){
    float4 o = make_float4(acc[q][0],acc[q][1],acc[q][2],acc[q][3]);
    *reinterpret_cast<float4*>(&C[(size_t)(m0+mg*8+q)*HF_ + c0 + cg*4]) = o;
  }
}

// ---- el/er: unchanged ----
__global__ __launch_bounds__(256) void eler_emu(const float* __restrict__ g, const float* __restrict__ a,
                                                float* __restrict__ el, float* __restrict__ er){
  const int gid = blockIdx.x*256 + threadIdx.x;   // (row, h)
  const int row = gid >> 3, h = gid & 7;
  const float* gr = g + (size_t)row*HF_ + h*64;
  float pl = 0.f, pr = 0.f;
  for (int f=0; f<64; ++f){
    pl = f_add(pl, f_mul(gr[f], a[f]));
    pr = f_add(pr, f_mul(gr[f], a[64+f]));
  }
  el[(size_t)row*NH_+h] = pl;
  er[(size_t)row*NH_+h] = pr;
}

// ---- attention: VERBATIM round 18 (known-pass; scalar LDS only). ----
__global__ __launch_bounds__(256) void att_sp(const float* __restrict__ g, const float* __restrict__ el,
                                              const float* __restrict__ er, const float* __restrict__ adjc,
                                              const unsigned short* __restrict__ lists,
                                              const int* __restrict__ cnts,
                                              float* __restrict__ hout){
  const int bid = swz8(blockIdx.x, gridDim.x);
  const int it = bid & 31, h = (bid>>5)&7, bc = bid>>8;
  const int i0 = it*16;
  __shared__ float er_s[512];
  __shared__ float el_s[16];
  __shared__ unsigned short list_s[16][128];
  __shared__ float pval_s[16][128];
  __shared__ int   cnt_s[16];
  __shared__ float m_s[16], den_s[16];
  __shared__ float rs[16][33];
  __shared__ float dense_s[513];   // overflow-fallback only
  __shared__ float red[256];       // overflow-fallback only
  const int t = threadIdx.x;
  if (t < 16){ el_s[t] = el[((size_t)(bc*N_) + i0 + t)*NH_ + h]; cnt_s[t] = cnts[bc*N_+i0+t]; }
  er_s[t]     = er[((size_t)(bc*N_) + t)*NH_ + h];
  er_s[t+256] = er[((size_t)(bc*N_) + t + 256)*NH_ + h];
  {
    const int r = t>>4, off = (t&15)*8;
    const unsigned short* lp = lists + ((size_t)(bc*N_)+i0+r)*128 + off;
    #pragma unroll
    for (int q=0;q<8;++q) list_s[r][off+q] = lp[q];
  }
  __syncthreads();
  const int ir = t>>4, l = t&15;
  // e in list order + per-lane max
  {
    const int cnt = cnt_s[ir];
    const float eli = el_s[ir];
    float mx = -INFINITY;
    if (cnt <= 128){
      for (int kk=l; kk<cnt; kk+=16){
        const float e = lrelu_np(f_add(eli, er_s[list_s[ir][kk]]));
        pval_s[ir][kk] = e;
        mx = fmaxf(mx, e);
      }
    }
    rs[ir][l] = mx;
  }
  __syncthreads();
  if (t < 16){
    float m = rs[t][0];
    #pragma unroll
    for (int u=1;u<16;++u) m = fmaxf(m, rs[t][u]);
    m_s[t] = m;
  }
  __syncthreads();
  // exp over list
  {
    const int cnt = cnt_s[ir];
    const float mi = m_s[ir];
    if (cnt <= 128)
      for (int kk=l; kk<cnt; kk+=16)
        pval_s[ir][kk] = expf_cr(f_sub(pval_s[ir][kk], mi));
  }
  __syncthreads();
  // den: numpy pairwise via slot-sums (thread owns slots l and l+16 of row ir) — SCALAR
  {
    const int cnt = cnt_s[ir];
    if (cnt <= 128){
      #pragma unroll
      for (int ss=0; ss<2; ++ss){
        const int s = l + ss*16;
        float r = 0.f;
        for (int kk=0; kk<cnt; ++kk){
          const int j = list_s[ir][kk];
          const int slot = ((j>>7)<<3) | (j&7);
          if (slot == s) r = f_add(r, pval_s[ir][kk]);
        }
        rs[ir][s] = r;
      }
    }
  }
  __syncthreads();
  if (t < 16 && cnt_s[t] <= 128){
    float pw[4];
    #pragma unroll
    for (int gq=0;gq<4;++gq){
      const float* rr = &rs[t][gq*8];
      pw[gq] = f_add(f_add(f_add(rr[0],rr[1]),f_add(rr[2],rr[3])),
                     f_add(f_add(rr[4],rr[5]),f_add(rr[6],rr[7])));
    }
    den_s[t] = f_add(f_add(pw[0],pw[1]), f_add(pw[2],pw[3]));
  }
  __syncthreads();
  // div over list
  {
    const int cnt = cnt_s[ir];
    const float di = den_s[ir];
    if (cnt <= 128)
      for (int kk=l; kk<cnt; kk+=16)
        pval_s[ir][kk] = f_div(pval_s[ir][kk], di);
  }
  __syncthreads();
  // aggregation: sparse j-ascending chain per (row, f) — SCALAR
  {
    const int f = t & 63, iw = t >> 6;
    const float* gcol = g + (size_t)(bc*N_)*HF_ + h*64 + f;
    const size_t ob = (size_t)(bc*N_) + i0;
    #pragma unroll
    for (int q=0;q<4;++q){
      const int i = iw + q*4;
      const int cnt = cnt_s[i];
      if (cnt > 128) continue;
      float a = 0.f;
      for (int kk=0; kk<cnt; ++kk){
        const int j = list_s[i][kk];
        a = f_add(a, f_mul(pval_s[i][kk], gcol[(size_t)j*HF_]));
      }
      hout[(ob+i)*HF_ + h*64 + f] = lrelu_np(a);
    }
  }
  // dense fallback for overflow rows (cnt>128; kept for unconditional correctness)
  for (int i=0;i<16;++i){
    if (cnt_s[i] <= 128) continue;
    __syncthreads();
    const int gi = i0 + i;
    const float eli = el_s[i];
    for (int s=0;s<2;++s){
      const int j = t + s*256;
      const float av = adjc[((size_t)(bc*N_)+gi)*N_ + j];
      const bool mask = (av != 0.f) || (gi == j);
      dense_s[j] = mask ? lrelu_np(f_add(eli, er_s[j])) : -1000.0f;
    }
    __syncthreads();
    red[t] = fmaxf(dense_s[t], dense_s[t+256]);
    __syncthreads();
    for (int s2=128; s2>=1; s2>>=1){ if (t<s2) red[t]=fmaxf(red[t],red[t+s2]); __syncthreads(); }
    const float mi = red[0];
    __syncthreads();
    for (int s=0;s<2;++s){
      const int j = t + s*256;
      const float v = dense_s[j];
      dense_s[j] = (v == -1000.0f) ? 0.0f : expf_cr(f_sub(v, mi));
    }
    __syncthreads();
    if (t < 32){
      const int gq = t>>3, ll = t&7;
      float r = dense_s[gq*128 + ll];
      for (int m2=1;m2<16;++m2) r = f_add(r, dense_s[gq*128 + m2*8 + ll]);
      rs[0][t] = r;
    }
    __syncthreads();
    if (t == 0){
      float pw[4];
      for (int gq=0;gq<4;++gq){
        const float* rr = &rs[0][gq*8];
        pw[gq] = f_add(f_add(f_add(rr[0],rr[1]),f_add(rr[2],rr[3])),
                       f_add(f_add(rr[4],rr[5]),f_add(rr[6],rr[7])));
      }
      den_s[0] = f_add(f_add(pw[0],pw[1]), f_add(pw[2],pw[3]));
    }
    __syncthreads();
    {
      const float di = den_s[0];
      for (int s=0;s<2;++s){ const int j=t+s*256; dense_s[j] = f_div(dense_s[j], di); }
    }
    __syncthreads();
    if (t < 64){
      const float* gcol = g + (size_t)(bc*N_)*HF_ + h*64 + t;
      float a = 0.f;
      for (int j=0;j<512;++j) a = f_add(a, f_mul(dense_s[j], gcol[(size_t)j*HF_]));
      hout[((size_t)(bc*N_)+gi)*HF_ + h*64 + t] = lrelu_np(a);
    }
  }
}

// ---- scores: unchanged ----
__global__ __launch_bounds__(256) void scores_emu(const float* __restrict__ h2, const float* __restrict__ Wp,
                                                  const float* __restrict__ bp, float* __restrict__ sc){
  const int r = blockIdx.x*256 + threadIdx.x;   // (bc, n)
  const float* hr = h2 + (size_t)r*HF_;
  float q0=0,q1=0,q2=0,q3=0,q4=0,q5=0,q6=0,q7=0;
  for (int k=0;k<512;k+=8){
    q0=f_fma(hr[k+0],Wp[k+0],q0); q1=f_fma(hr[k+1],Wp[k+1],q1);
    q2=f_fma(hr[k+2],Wp[k+2],q2); q3=f_fma(hr[k+3],Wp[k+3],q3);
    q4=f_fma(hr[k+4],Wp[k+4],q4); q5=f_fma(hr[k+5],Wp[k+5],q5);
    q6=f_fma(hr[k+6],Wp[k+6],q6); q7=f_fma(hr[k+7],Wp[k+7],q7);
  }
  const float d = f_add(f_add(f_add(q0,q4),f_add(q1,q5)), f_add(f_add(q2,q6),f_add(q3,q7)));
  sc[r] = f_add(d, bp[0]);
}

// ---- stable top-256 rank counting (unchanged) ----
__global__ __launch_bounds__(512) void topk_f(const float* __restrict__ sc, int* __restrict__ idx){
  __shared__ float sl[512];
  const int b = blockIdx.x, t = threadIdx.x;
  if (t < 256) idx[b*256+t] = t;
  sl[t] = sc[(size_t)b*N_+t];
  __syncthreads();
  const float mine = sl[t];
  int cnt = 0;
  for (int j=0;j<N_;++j){
    const float v = sl[j];
    cnt += (v > mine) || (v == mine && j < t);
  }
  if (cnt < 256) idx[b*256+cnt] = t;
}

__global__ __launch_bounds__(128) void gather_f(const float* __restrict__ h2, const int* __restrict__ idx,
                                                float* __restrict__ outc){
  const int r = blockIdx.x;
  const int bc = r>>8, kk = r&255;
  const int n = idx[bc*256+kk] & (N_-1);
  const int t = threadIdx.x;
  const float4 v = *reinterpret_cast<const float4*>(&h2[(size_t)(bc*N_+n)*HF_ + t*4]);
  *reinterpret_cast<float4*>(&outc[(size_t)(bc*256+kk)*HF_ + t*4]) = v;
}

extern "C" void kernel_launch(void* const* d_in, const int* in_sizes, int n_in,
                              void* d_out, int out_size, void* d_ws, size_t ws_size,
                              hipStream_t stream){
  const float* x   = (const float*)d_in[0];
  const float* adj = (const float*)d_in[1];
  const float* W1  = (const float*)d_in[2];
  const float* a1  = (const float*)d_in[3];
  const float* W2  = (const float*)d_in[4];
  const float* a2  = (const float*)d_in[5];
  const float* Wp  = (const float*)d_in[6];
  const float* bp  = (const float*)d_in[7];

  // per-batch: g/h1/h2 1MiB each + el/er 16KiB + sc 2KiB + idx 1KiB + lists 128KiB + cnts 2KiB
  const size_t per = 3314688;
  int C = B_;
  while (C > 1 && per*(size_t)C > ws_size) C >>= 1;

  char* w    = (char*)d_ws;
  float* g   = (float*)w;
  float* h1  = (float*)(w + (size_t)C*1048576);
  float* h2  = (float*)(w + (size_t)2*C*1048576);
  float* el  = (float*)(w + (size_t)3*C*1048576);
  float* er  = el + (size_t)C*4096;
  float* sc  = er + (size_t)C*4096;
  int*  idx  = (int*)(sc + (size_t)C*512);
  unsigned short* lists = (unsigned short*)((char*)idx + (size_t)C*1024);
  int*  cnts = (int*)((char*)lists + (size_t)C*131072);

  for (int b0 = 0; b0 < B_; b0 += C){
    const float* xc   = x   + (size_t)b0*N_*K_;
    const float* adjc = adj + (size_t)b0*N_*N_;
    float* outc = (float*)d_out + (size_t)b0*256*HF_;
    const int M = C*N_;
    dim3 gg(HF_/64, M/128);
    build_lists<<<C*128, 256, 0, stream>>>(adjc, lists, cnts);
    // layer 1
    gemm_t<<<gg, 256, 0, stream>>>(xc, W1, g);
    eler_emu<<<(M*NH_)/256, 256, 0, stream>>>(g, a1, el, er);
    att_sp<<<C*NH_*32, 256, 0, stream>>>(g, el, er, adjc, lists, cnts, h1);
    // layer 2
    gemm_t<<<gg, 256, 0, stream>>>(h1, W2, g);
    eler_emu<<<(M*NH_)/256, 256, 0, stream>>>(g, a2, el, er);
    att_sp<<<C*NH_*32, 256, 0, stream>>>(g, el, er, adjc, lists, cnts, h2);
    // pool
    scores_emu<<<M/256, 256, 0, stream>>>(h2, Wp, bp, sc);
    topk_f<<<C, 512, 0, stream>>>(sc, idx);
    gather_f<<<C*256, 128, 0, stream>>>(h2, idx, outc);
  }
}